// Round 14
// baseline (121.963 us; speedup 1.0000x reference)
//
#include <hip/hip_runtime.h>

// GCN forward on MI355X (gfx950).
// R14: fuse bfinal + gather1 into k_spmm1 — one block per 128-row bucket
// sorts its edges in LDS (writing pairs/offs2 for layer 2) then gathers
// its own rows with 16 rows/wave (256 edges/wave = 32 latency batches vs
// 2 in the old 1-row/wave gather). gather2 gets 8 rows/wave. 5 dispatches.

#define N_NODES 50000
#define N_EDGES 800000
#define IN_DIM  128
#define HID_DIM 64
#define OUT_DIM 64

#define RB   128                      // rows per bucket
#define NBK  ((N_NODES + RB - 1) / RB)            // 391
#define EPB  4096                     // edges per bscatter block
#define NBLK_E ((N_EDGES + EPB - 1) / EPB)        // 196
#define BCAP 2560                     // padded bucket region; E=2046, +11sigma
#define GEMM1_GRID ((N_NODES + 31) / 32)          // 1563

typedef __attribute__((ext_vector_type(8))) short bf16x8;
typedef __attribute__((ext_vector_type(4))) float f32x4;

__device__ inline unsigned short f2bf(float x) {   // RNE fp32 -> bf16
    unsigned u = __float_as_uint(x);
    return (unsigned short)((u + 0x7FFFu + ((u >> 16) & 1u)) >> 16);
}
__device__ inline float bf2f(unsigned v) {
    return __uint_as_float(v << 16);
}

// ---------------- prep: weight transpose+bf16 convert, bcur zero ------
__global__ __launch_bounds__(256) void k_prep(
    const float* __restrict__ W1, unsigned short* __restrict__ Wt1,
    const float* __restrict__ W2, unsigned short* __restrict__ Wt2,
    int* __restrict__ bcur)
{
    int b = blockIdx.x, t = threadIdx.x;
    if (b < 32) {                       // IN_DIM*HID_DIM = 8192 = 32*256
        int e = b * 256 + t;
        int c = e / IN_DIM, k = e % IN_DIM;
        Wt1[c * IN_DIM + k] = f2bf(W1[k * HID_DIM + c]);
    } else if (b < 48) {                // HID_DIM*OUT_DIM = 4096 = 16*256
        int e2 = (b - 32) * 256 + t;
        int c = e2 / HID_DIM, k = e2 % HID_DIM;
        Wt2[c * HID_DIM + k] = f2bf(W2[k * OUT_DIM + c]);
    } else {
        for (int i = t; i < NBK; i += 256) bcur[i] = 0;
    }
}

// ---------------- MFMA GEMM body (32 rows/block, 4 waves) -------------
template <int K, bool IN_BF16>
__device__ __forceinline__ void gemm_body(
    unsigned short* __restrict__ Al, unsigned short* __restrict__ Bl,
    const void* __restrict__ Xv, const unsigned short* __restrict__ Wt,
    unsigned short* __restrict__ out, int bid, int t)
{
    int m0 = bid * 32;
    #pragma unroll
    for (int i = 0; i < K / 32; ++i) {
        int u4 = i * 256 + t;                 // uint4 index
        int col = (u4 * 8) / K, k = (u4 * 8) % K;
        uint4 w = ((const uint4*)Wt)[u4];
        int byte = (col * K + k) * 2;
        byte ^= ((col & 7) << 4);
        *(uint4*)((char*)Bl + byte) = w;
    }
    if (IN_BF16) {
        const unsigned short* X = (const unsigned short*)Xv;
        int row = t / (K / 8), k = (t % (K / 8)) * 8;
        int grow = m0 + row;
        uint4 v = make_uint4(0, 0, 0, 0);
        if (grow < N_NODES)
            v = *(const uint4*)(X + (size_t)grow * K + k);
        int byte = (row * K + k) * 2;
        byte ^= ((row & 7) << 4);
        *(uint4*)((char*)Al + byte) = v;
    } else {
        const float* X = (const float*)Xv;
        #pragma unroll
        for (int i = 0; i < K / 64; ++i) {
            int f8 = i * 256 + t;             // 8-float group
            int row = (f8 * 8) / K, k = (f8 * 8) % K;
            int grow = m0 + row;
            float4 xa = make_float4(0.f, 0.f, 0.f, 0.f), xb = xa;
            if (grow < N_NODES) {
                const float4* src = (const float4*)(X + (size_t)grow * K + k);
                xa = src[0];
                xb = src[1];
            }
            uint4 v;
            v.x = (unsigned)f2bf(xa.x) | ((unsigned)f2bf(xa.y) << 16);
            v.y = (unsigned)f2bf(xa.z) | ((unsigned)f2bf(xa.w) << 16);
            v.z = (unsigned)f2bf(xb.x) | ((unsigned)f2bf(xb.y) << 16);
            v.w = (unsigned)f2bf(xb.z) | ((unsigned)f2bf(xb.w) << 16);
            int byte = (row * K + k) * 2;
            byte ^= ((row & 7) << 4);
            *(uint4*)((char*)Al + byte) = v;
        }
    }
    __syncthreads();

    int w = t >> 6, l = t & 63;
    int lr0 = (w & 1) * 16;
    int c0  = (w >> 1) * 32;
    int lrow = lr0 + (l & 15);
    int kb = (l >> 4) * 8;
    int col0 = c0 + (l & 15), col1 = col0 + 16;
    f32x4 acc0 = {0.f, 0.f, 0.f, 0.f}, acc1 = {0.f, 0.f, 0.f, 0.f};
    #pragma unroll
    for (int kc = 0; kc < K / 32; ++kc) {
        int ka = kc * 32 + kb;
        int ab = (lrow * K + ka) * 2;  ab ^= ((lrow & 7) << 4);
        int bb0 = (col0 * K + ka) * 2; bb0 ^= ((col0 & 7) << 4);
        int bb1 = (col1 * K + ka) * 2; bb1 ^= ((col1 & 7) << 4);
        bf16x8 a  = *(const bf16x8*)((const char*)Al + ab);
        bf16x8 b0 = *(const bf16x8*)((const char*)Bl + bb0);
        bf16x8 b1 = *(const bf16x8*)((const char*)Bl + bb1);
        acc0 = __builtin_amdgcn_mfma_f32_16x16x32_bf16(a, b0, acc0, 0, 0, 0);
        acc1 = __builtin_amdgcn_mfma_f32_16x16x32_bf16(a, b1, acc1, 0, 0, 0);
    }
    int grow0 = m0 + lr0 + (l >> 4) * 4;
    #pragma unroll
    for (int j = 0; j < 4; ++j) {
        int gr = grow0 + j;
        if (gr < N_NODES) {
            out[(size_t)gr * 64 + col0] = f2bf(acc0[j]);
            out[(size_t)gr * 64 + col1] = f2bf(acc1[j]);
        }
    }
}

// ---------------- mega1: GEMM1 (blocks < GEMM1_GRID) || bscatter ------
// bscatter: rank -> in-block scan -> LDS bucket-sort -> coalesced
// streaming writeout. word0 = col:16 | rowlow:7 (bits 16-22) | bucket:9
// (bits 23-31). smem: sbuf 32768 | lc @32768 (391) | scr @34432 (512) |
// lbase @36480 (391) -> 38044B.
__global__ __launch_bounds__(256) void k_mega1(
    const float* __restrict__ X, const unsigned short* __restrict__ Wt1,
    unsigned short* __restrict__ support,
    const int* __restrict__ erow, const int* __restrict__ ecol,
    const float* __restrict__ eval_, int* __restrict__ bcur,
    uint2* __restrict__ bucketed)
{
    __shared__ __align__(16) unsigned char smem[38080];
    int t = threadIdx.x;
    if (blockIdx.x < GEMM1_GRID) {
        gemm_body<IN_DIM, false>((unsigned short*)smem,
                                 (unsigned short*)(smem + 8192),
                                 X, Wt1, support, blockIdx.x, t);
        return;
    }
    uint2* sbuf  = (uint2*)smem;
    int*   lc    = (int*)(smem + 32768);
    int*   scr   = (int*)(smem + 34432);
    int*   lbase = (int*)(smem + 36480);
    int blk = blockIdx.x - GEMM1_GRID;
    for (int i = t; i < NBK; i += 256) lc[i] = 0;
    __syncthreads();
    int base = blk * EPB;
    int ne_total = min(EPB, N_EDGES - base);
    int bkt[16], rnk[16];
    unsigned w0v[16], vv[16];
    #pragma unroll 4
    for (int i = 0; i < 16; ++i) {
        int e = base + i * 256 + t;
        bkt[i] = -1;
        if (e < N_EDGES) {
            unsigned r = (unsigned)erow[e];
            bkt[i] = (int)(r >> 7);
            w0v[i] = (unsigned)ecol[e] | ((r & 127u) << 16)
                     | ((r >> 7) << 23);
            vv[i] = __float_as_uint(eval_[e]);
            rnk[i] = atomicAdd(&lc[bkt[i]], 1);
        }
    }
    __syncthreads();
    // exclusive scan of lc[0..NBK) using two 256-element passes
    // pass over 512-wide logical array with 256 threads: serial 2-elem fold
    int c0 = lc[t], c1 = (t + 256 < NBK) ? lc[t + 256] : 0;
    scr[t] = c0 + c1;                    // scr[t] = lc[t] + lc[t+256]
    __syncthreads();
    #pragma unroll
    for (int off = 1; off < 256; off <<= 1) {
        int add = (t >= off) ? scr[t - off] : 0;
        __syncthreads();
        scr[t] += add;
        __syncthreads();
    }
    // exclusive prefix for element t: scr[t-1]; for t+256: scr[255 of first..]
    // simpler mapping: order is [0..255] then [256..NBK): prefix(t) =
    // scr[t]-c0-c1 + 0 ... need care: define P = scr[t] - (c0+c1) =
    // sum of (lc[i]+lc[i+256]) for i<t. That interleaves. Use direct layout:
    // element t has exclusive = P + 0; element t+256 has exclusive =
    // P_full(256 wrap)... -- instead recompute exactly:
    __syncthreads();
    // store pairwise-exclusive into lbase region temporarily
    int pairExcl = scr[t] - (c0 + c1);   // sum over i<t of (lc[i]+lc[i+256])
    // total of first halves for i<256:
    __shared__ int totFirst;
    if (t == 255) totFirst = 0;          // placeholder init
    __syncthreads();
    // compute sum of all c0 via last pairExcl + ... do a second tiny scan:
    // excl(t)       = sum_{i<t} lc[i]
    // excl(t+256)   = sum_all_first + sum_{i<t} lc[i+256]
    // where sum_{i<t} lc[i] and sum_{i<t} lc[i+256] need separate scans.
    // Redo with two sequential 256-wide scans (cheap, 8 barriers each):
    scr[t] = c0;
    __syncthreads();
    #pragma unroll
    for (int off = 1; off < 256; off <<= 1) {
        int add = (t >= off) ? scr[t - off] : 0;
        __syncthreads();
        scr[t] += add;
        __syncthreads();
    }
    int exclA = scr[t] - c0;             // exclusive among first 256
    int sumA  = scr[255];                // needs barrier before reuse
    __syncthreads();
    scr[t] = c1;
    __syncthreads();
    #pragma unroll
    for (int off = 1; off < 256; off <<= 1) {
        int add = (t >= off) ? scr[t - off] : 0;
        __syncthreads();
        scr[t] += add;
        __syncthreads();
    }
    int exclB = sumA + scr[t] - c1;      // exclusive for element t+256
    __syncthreads();
    scr[t] = exclA;                      // bucket t start in sbuf
    if (t + 256 < NBK) lbase[t + 256] = 0;  // init (filled below)
    __syncthreads();
    // publish starts for high half via lbase-as-scratch then move:
    if (t + 256 < NBK) scr[t + 256 - 256] = exclA; // no-op keep
    // write high-half starts into a dedicated slot: reuse lc (counts still
    // needed for reservation) -> use separate pass: store exclB via sbuf?
    // Simplest: keep high-half starts in registers via shared array:
    __shared__ int scrHi[256];
    scrHi[t] = exclB;
    // reserve global runs
    if (t < NBK && t < 256)
        lbase[t] = c0 ? atomicAdd(&bcur[t], c0) : 0;
    if (t + 256 < NBK)
        lbase[t + 256] = c1 ? atomicAdd(&bcur[t + 256], c1) : 0;
    __syncthreads();
    // place edges sorted by bucket into sbuf
    #pragma unroll 4
    for (int i = 0; i < 16; ++i)
        if (bkt[i] >= 0) {
            int st = (bkt[i] < 256) ? scr[bkt[i]] : scrHi[bkt[i] - 256];
            sbuf[st + rnk[i]] = make_uint2(w0v[i], vv[i]);
        }
    __syncthreads();
    // coalesced streaming writeout
    #pragma unroll 4
    for (int i = 0; i < 16; ++i) {
        int idx = i * 256 + t;
        if (idx < ne_total) {
            uint2 p = sbuf[idx];
            int bk = (int)(p.x >> 23);
            int st = (bk < 256) ? scr[bk] : scrHi[bk - 256];
            bucketed[(size_t)bk * BCAP + lbase[bk] + (idx - st)] = p;
        }
    }
}

// ---------------- spmm1: per-bucket sort + pairs/offs2 + gather1 ------
// 512 thr (8 waves), one block per 128-row bucket. After the LDS sort,
// wave w gathers rows w*16..w*16+15 (256 edges/wave = 32 latency batches)
// reading (col,val) from sorted LDS arrays; writes agg1 = relu(agg+b1) bf16.
__global__ __launch_bounds__(512) void k_spmm1(
    const int* __restrict__ bcur, const uint2* __restrict__ bucketed,
    const unsigned short* __restrict__ support, const float* __restrict__ b1,
    uint2* __restrict__ pairs, int2* __restrict__ offs2,
    unsigned short* __restrict__ agg1)
{
    __shared__ uint2 ebuf[BCAP];           // 20 KB
    __shared__ unsigned short scol[BCAP];  // 5 KB
    __shared__ float sval[BCAP];           // 10 KB
    __shared__ int rcnt[RB], lstart[RB], rcur[RB];
    int t = threadIdx.x, b = blockIdx.x;
    int ne = bcur[b];
    size_t base0 = (size_t)b * BCAP;
    if (t < RB) rcnt[t] = 0;
    __syncthreads();
    for (int i = t; i < ne; i += 512) {
        uint2 p = bucketed[base0 + i];
        ebuf[i] = p;
        atomicAdd(&rcnt[(p.x >> 16) & 127], 1);
    }
    __syncthreads();
    if (t < 64) {                          // wave-0 scan of 128 counts
        int c0 = rcnt[2 * t], c1 = rcnt[2 * t + 1];
        int s = c0 + c1, inc = s;
        #pragma unroll
        for (int off = 1; off < 64; off <<= 1) {
            int o = __shfl_up(inc, off, 64);
            if (t >= off) inc += o;
        }
        int excl = inc - s;
        lstart[2 * t] = excl;
        lstart[2 * t + 1] = excl + c0;
        rcur[2 * t] = excl;
        rcur[2 * t + 1] = excl + c0;
        int gr = b * RB + 2 * t;
        int gs = (int)base0 + excl;
        if (gr < N_NODES) offs2[gr] = make_int2(gs, gs + c0);
        if (gr + 1 < N_NODES) offs2[gr + 1] = make_int2(gs + c0, gs + c0 + c1);
    }
    __syncthreads();
    for (int i = t; i < ne; i += 512) {    // row-sort into LDS + pairs
        uint2 p = ebuf[i];
        int row = (p.x >> 16) & 127;
        int pos = atomicAdd(&rcur[row], 1);
        scol[pos] = (unsigned short)(p.x & 0xFFFFu);
        sval[pos] = __uint_as_float(p.y);
        pairs[base0 + pos] = make_uint2(p.x & 0xFFFFu, p.y);
    }
    __syncthreads();
    int w = t >> 6, d = t & 63;
    #pragma unroll 1
    for (int j = 0; j < 16; ++j) {
        int rl = w * 16 + j;
        int gr = b * RB + rl;
        if (gr >= N_NODES) continue;
        int e0 = lstart[rl], e1 = rcur[rl];
        float a[8];
        a[0] = b1[d];
        #pragma unroll
        for (int i = 1; i < 8; ++i) a[i] = 0.f;
        int e = e0;
        for (; e + 8 <= e1; e += 8) {
            unsigned short c[8];
            float vv[8];
            #pragma unroll
            for (int i = 0; i < 8; ++i) { c[i] = scol[e + i]; vv[i] = sval[e + i]; }
            unsigned v[8];
            #pragma unroll
            for (int i = 0; i < 8; ++i) v[i] = support[(size_t)c[i] * 64u + d];
            #pragma unroll
            for (int i = 0; i < 8; ++i) a[i] = fmaf(vv[i], bf2f(v[i]), a[i]);
        }
        for (; e < e1; ++e)
            a[0] = fmaf(sval[e], bf2f(support[(size_t)scol[e] * 64u + d]), a[0]);
        float acc = ((a[0] + a[1]) + (a[2] + a[3])) +
                    ((a[4] + a[5]) + (a[6] + a[7]));
        acc = fmaxf(acc, 0.f);             // relu (layer 1)
        agg1[(size_t)gr * 64 + d] = f2bf(acc);
    }
}

// ---------------- gather2: 8 rows/wave, fp32 out ----------------------
__global__ __launch_bounds__(256) void k_gather2(
    const int2* __restrict__ offs2, const uint2* __restrict__ pairs,
    const unsigned short* __restrict__ dense, const float* __restrict__ bias,
    float* __restrict__ outp)
{
    int t = threadIdx.x;
    int w = t >> 6, d = t & 63;
    int rbase = __builtin_amdgcn_readfirstlane((blockIdx.x * 4 + w) * 8);
    #pragma unroll 1
    for (int j = 0; j < 8; ++j) {
        int r = rbase + j;
        if (r >= N_NODES) continue;
        int2 oe = offs2[r];
        int e0 = oe.x, e1 = oe.y;
        float a[8];
        a[0] = bias[d];
        #pragma unroll
        for (int i = 1; i < 8; ++i) a[i] = 0.f;
        int e = e0;
        for (; e + 8 <= e1; e += 8) {
            uint2 p[8];
            #pragma unroll
            for (int i = 0; i < 8; ++i) p[i] = pairs[e + i];
            unsigned v[8];
            #pragma unroll
            for (int i = 0; i < 8; ++i) v[i] = dense[(size_t)p[i].x * 64u + d];
            #pragma unroll
            for (int i = 0; i < 8; ++i)
                a[i] = fmaf(__uint_as_float(p[i].y), bf2f(v[i]), a[i]);
        }
        for (; e < e1; ++e) {
            uint2 p = pairs[e];
            a[0] = fmaf(__uint_as_float(p.y),
                        bf2f(dense[(size_t)p.x * 64u + d]), a[0]);
        }
        float acc = ((a[0] + a[1]) + (a[2] + a[3])) +
                    ((a[4] + a[5]) + (a[6] + a[7]));
        outp[(size_t)r * 64 + d] = acc;
    }
}

// ---------------- GEMM2 standalone (K=64, bf16 in) --------------------
__global__ __launch_bounds__(256) void k_gemm2(
    const unsigned short* __restrict__ X, const unsigned short* __restrict__ Wt,
    unsigned short* __restrict__ out)
{
    __shared__ unsigned short Al[32 * HID_DIM];
    __shared__ unsigned short Bl[64 * HID_DIM];
    gemm_body<HID_DIM, true>(Al, Bl, X, Wt, out, blockIdx.x, threadIdx.x);
}

extern "C" void kernel_launch(void* const* d_in, const int* in_sizes, int n_in,
                              void* d_out, int out_size, void* d_ws, size_t ws_size,
                              hipStream_t stream)
{
    const float* x     = (const float*)d_in[0];
    const int*   erow  = (const int*)d_in[1];
    const int*   ecol  = (const int*)d_in[2];
    const float* eval_ = (const float*)d_in[3];
    const float* W1    = (const float*)d_in[4];
    const float* b1    = (const float*)d_in[5];
    const float* W2    = (const float*)d_in[6];
    const float* b2    = (const float*)d_in[7];
    float* out = (float*)d_out;

    // ws (~30 MB): pairs 8.0MB | bucketed 8.0MB | support bf16 6.4MB |
    // agg1 bf16 6.4MB | Wt1 | Wt2 | bcur | offs2
    uint2* pairs    = (uint2*)d_ws;
    uint2* bucketed = pairs + (size_t)NBK * BCAP;
    unsigned short* support = (unsigned short*)(bucketed + (size_t)NBK * BCAP);
    unsigned short* agg1 = support + (size_t)N_NODES * 64;
    unsigned short* Wt1 = agg1 + (size_t)N_NODES * 64;
    unsigned short* Wt2 = Wt1 + IN_DIM * HID_DIM;
    int*  bcur  = (int*)(Wt2 + HID_DIM * OUT_DIM);
    int2* offs2 = (int2*)(bcur + NBK + 1);     // 392 ints -> 8B-aligned

    // 5 dispatches
    k_prep<<<49, 256, 0, stream>>>(W1, Wt1, W2, Wt2, bcur);
    k_mega1<<<GEMM1_GRID + NBLK_E, 256, 0, stream>>>(
        x, Wt1, support, erow, ecol, eval_, bcur, bucketed);
    k_spmm1<<<NBK, 512, 0, stream>>>(
        bcur, bucketed, support, b1, pairs, offs2, agg1);
    k_gemm2<<<GEMM1_GRID, 256, 0, stream>>>(agg1, Wt2, support);
    k_gather2<<<(N_NODES + 31) / 32, 256, 0, stream>>>(
        offs2, pairs, support, b2, out);
}

// Round 15
// 98.856 us; speedup vs baseline: 1.2337x; 1.2337x over previous
//
#include <hip/hip_runtime.h>

// GCN forward on MI355X (gfx950).
// R15: UNFUSED pipeline. R14's spmm1 fusion (391 blocks) killed gather
// parallelism (48us). R10-R13's mega1 fusion forced 38KB LDS on all
// blocks (4/CU cap) and in-order block dispatch serialized GEMM/bscatter
// anyway. Now: every kernel standalone at its own best geometry, lean
// bscatter (EPB=1024, 782 blocks, single scan, coalesced sorted writeout).
// 8 dispatches, clean per-kernel profile.

#define N_NODES 50000
#define N_EDGES 800000
#define IN_DIM  128
#define HID_DIM 64
#define OUT_DIM 64

#define RB   256                      // rows per bucket (bfinal granularity)
#define NB   ((N_NODES + RB - 1) / RB)            // 196
#define EPB  1024                     // edges per bscatter block
#define NBLK_E ((N_EDGES + EPB - 1) / EPB)        // 782
#define BCAP 5120                     // padded bucket region; E=4081, 16sigma
#define GEMM_GRID ((N_NODES + 31) / 32)           // 1563

typedef __attribute__((ext_vector_type(8))) short bf16x8;
typedef __attribute__((ext_vector_type(4))) float f32x4;

__device__ inline unsigned short f2bf(float x) {   // RNE fp32 -> bf16
    unsigned u = __float_as_uint(x);
    return (unsigned short)((u + 0x7FFFu + ((u >> 16) & 1u)) >> 16);
}
__device__ inline float bf2f(unsigned v) {
    return __uint_as_float(v << 16);
}

// ---------------- prep: weight transpose+bf16 convert, bcur zero ------
__global__ __launch_bounds__(256) void k_prep(
    const float* __restrict__ W1, unsigned short* __restrict__ Wt1,
    const float* __restrict__ W2, unsigned short* __restrict__ Wt2,
    int* __restrict__ bcur)
{
    int b = blockIdx.x, t = threadIdx.x;
    if (b < 32) {                       // IN_DIM*HID_DIM = 8192 = 32*256
        int e = b * 256 + t;
        int c = e / IN_DIM, k = e % IN_DIM;
        Wt1[c * IN_DIM + k] = f2bf(W1[k * HID_DIM + c]);
    } else if (b < 48) {                // HID_DIM*OUT_DIM = 4096 = 16*256
        int e2 = (b - 32) * 256 + t;
        int c = e2 / HID_DIM, k = e2 % HID_DIM;
        Wt2[c * HID_DIM + k] = f2bf(W2[k * OUT_DIM + c]);
    } else {
        if (t < NB) bcur[t] = 0;
    }
}

// ---------------- bscatter: 1024 edges/block, LDS sort, coalesced out -
// word0 = col:16 | rowlow:8 (bits 16-23) | bucket:8 (bits 24-31).
__global__ __launch_bounds__(256) void k_bscatter(
    const int* __restrict__ erow, const int* __restrict__ ecol,
    const float* __restrict__ eval_, int* __restrict__ bcur,
    uint2* __restrict__ bucketed)
{
    __shared__ uint2 sbuf[EPB];         // 8 KB
    __shared__ int lc[NB];
    __shared__ int scr[256];
    __shared__ int lbase[NB];
    int t = threadIdx.x;
    if (t < NB) lc[t] = 0;
    __syncthreads();
    int base = blockIdx.x * EPB;
    int ne = min(EPB, N_EDGES - base);
    int bkt[4], rnk[4];
    unsigned w0v[4], vv[4];
    #pragma unroll
    for (int i = 0; i < 4; ++i) {
        int e = base + i * 256 + t;
        bkt[i] = -1;
        if (e < N_EDGES) {
            unsigned r = (unsigned)erow[e];
            bkt[i] = (int)(r >> 8);
            w0v[i] = (unsigned)ecol[e] | ((r & 255u) << 16) | ((r >> 8) << 24);
            vv[i] = __float_as_uint(eval_[e]);
            rnk[i] = atomicAdd(&lc[bkt[i]], 1);
        }
    }
    __syncthreads();
    // single 256-wide exclusive scan of lc[0..NB)
    int cnt = (t < NB) ? lc[t] : 0;
    scr[t] = cnt;
    __syncthreads();
    #pragma unroll
    for (int off = 1; off < 256; off <<= 1) {
        int add = (t >= off) ? scr[t - off] : 0;
        __syncthreads();
        scr[t] += add;
        __syncthreads();
    }
    int excl = scr[t] - cnt;
    __syncthreads();
    scr[t] = excl;                      // bucket start within sbuf
    if (t < NB) lbase[t] = cnt ? atomicAdd(&bcur[t], cnt) : 0;
    __syncthreads();
    // place edges bucket-sorted into sbuf
    #pragma unroll
    for (int i = 0; i < 4; ++i)
        if (bkt[i] >= 0)
            sbuf[scr[bkt[i]] + rnk[i]] = make_uint2(w0v[i], vv[i]);
    __syncthreads();
    // coalesced writeout in sorted order
    #pragma unroll
    for (int i = 0; i < 4; ++i) {
        int idx = i * 256 + t;
        if (idx < ne) {
            uint2 p = sbuf[idx];
            int bk = (int)(p.x >> 24);
            bucketed[(size_t)bk * BCAP + lbase[bk] + (idx - scr[bk])] = p;
        }
    }
}

// ---------------- bfinal: one block per 256-row bucket ----------------
// LDS-cache the bucket's edges; per-row count -> in-block scan ->
// offs2[row]=(start,end) -> row-sorted scatter into pairs.
__global__ __launch_bounds__(256) void k_bfinal(
    const int* __restrict__ bcur, const uint2* __restrict__ bucketed,
    uint2* __restrict__ pairs, int2* __restrict__ offs2)
{
    __shared__ uint2 ebuf[BCAP];        // 40 KB
    __shared__ int rcnt[256];
    __shared__ int rsc[256];
    int t = threadIdx.x, b = blockIdx.x;
    int ne = bcur[b];
    int base0 = b * BCAP;
    rcnt[t] = 0;
    __syncthreads();
    for (int i = t; i < ne; i += 256) {
        uint2 p = bucketed[(size_t)base0 + i];
        ebuf[i] = p;
        atomicAdd(&rcnt[(p.x >> 16) & 255], 1);
    }
    __syncthreads();
    int v = rcnt[t];
    rsc[t] = v;
    __syncthreads();
    #pragma unroll
    for (int off = 1; off < 256; off <<= 1) {
        int add = (t >= off) ? rsc[t - off] : 0;
        __syncthreads();
        rsc[t] += add;
        __syncthreads();
    }
    int start = base0 + rsc[t] - v;
    int gr = (b << 8) + t;
    if (gr < N_NODES) offs2[gr] = make_int2(start, start + v);
    rcnt[t] = start;                    // becomes row cursor
    __syncthreads();
    for (int i = t; i < ne; i += 256) {
        uint2 p = ebuf[i];
        int pos = atomicAdd(&rcnt[(p.x >> 16) & 255], 1);
        pairs[pos] = make_uint2(p.x & 0xFFFFu, p.y);
    }
}

// ---------------- MFMA GEMM body (32 rows/block, 4 waves) -------------
template <int K, bool IN_BF16>
__device__ __forceinline__ void gemm_body(
    unsigned short* __restrict__ Al, unsigned short* __restrict__ Bl,
    const void* __restrict__ Xv, const unsigned short* __restrict__ Wt,
    unsigned short* __restrict__ out, int bid, int t)
{
    int m0 = bid * 32;
    #pragma unroll
    for (int i = 0; i < K / 32; ++i) {
        int u4 = i * 256 + t;                 // uint4 index
        int col = (u4 * 8) / K, k = (u4 * 8) % K;
        uint4 w = ((const uint4*)Wt)[u4];
        int byte = (col * K + k) * 2;
        byte ^= ((col & 7) << 4);
        *(uint4*)((char*)Bl + byte) = w;
    }
    if (IN_BF16) {
        const unsigned short* X = (const unsigned short*)Xv;
        int row = t / (K / 8), k = (t % (K / 8)) * 8;
        int grow = m0 + row;
        uint4 v = make_uint4(0, 0, 0, 0);
        if (grow < N_NODES)
            v = *(const uint4*)(X + (size_t)grow * K + k);
        int byte = (row * K + k) * 2;
        byte ^= ((row & 7) << 4);
        *(uint4*)((char*)Al + byte) = v;
    } else {
        const float* X = (const float*)Xv;
        #pragma unroll
        for (int i = 0; i < K / 64; ++i) {
            int f8 = i * 256 + t;             // 8-float group
            int row = (f8 * 8) / K, k = (f8 * 8) % K;
            int grow = m0 + row;
            float4 xa = make_float4(0.f, 0.f, 0.f, 0.f), xb = xa;
            if (grow < N_NODES) {
                const float4* src = (const float4*)(X + (size_t)grow * K + k);
                xa = src[0];
                xb = src[1];
            }
            uint4 v;
            v.x = (unsigned)f2bf(xa.x) | ((unsigned)f2bf(xa.y) << 16);
            v.y = (unsigned)f2bf(xa.z) | ((unsigned)f2bf(xa.w) << 16);
            v.z = (unsigned)f2bf(xb.x) | ((unsigned)f2bf(xb.y) << 16);
            v.w = (unsigned)f2bf(xb.z) | ((unsigned)f2bf(xb.w) << 16);
            int byte = (row * K + k) * 2;
            byte ^= ((row & 7) << 4);
            *(uint4*)((char*)Al + byte) = v;
        }
    }
    __syncthreads();

    int w = t >> 6, l = t & 63;
    int lr0 = (w & 1) * 16;
    int c0  = (w >> 1) * 32;
    int lrow = lr0 + (l & 15);
    int kb = (l >> 4) * 8;
    int col0 = c0 + (l & 15), col1 = col0 + 16;
    f32x4 acc0 = {0.f, 0.f, 0.f, 0.f}, acc1 = {0.f, 0.f, 0.f, 0.f};
    #pragma unroll
    for (int kc = 0; kc < K / 32; ++kc) {
        int ka = kc * 32 + kb;
        int ab = (lrow * K + ka) * 2;  ab ^= ((lrow & 7) << 4);
        int bb0 = (col0 * K + ka) * 2; bb0 ^= ((col0 & 7) << 4);
        int bb1 = (col1 * K + ka) * 2; bb1 ^= ((col1 & 7) << 4);
        bf16x8 a  = *(const bf16x8*)((const char*)Al + ab);
        bf16x8 b0 = *(const bf16x8*)((const char*)Bl + bb0);
        bf16x8 b1 = *(const bf16x8*)((const char*)Bl + bb1);
        acc0 = __builtin_amdgcn_mfma_f32_16x16x32_bf16(a, b0, acc0, 0, 0, 0);
        acc1 = __builtin_amdgcn_mfma_f32_16x16x32_bf16(a, b1, acc1, 0, 0, 0);
    }
    int grow0 = m0 + lr0 + (l >> 4) * 4;
    #pragma unroll
    for (int j = 0; j < 4; ++j) {
        int gr = grow0 + j;
        if (gr < N_NODES) {
            out[(size_t)gr * 64 + col0] = f2bf(acc0[j]);
            out[(size_t)gr * 64 + col1] = f2bf(acc1[j]);
        }
    }
}

// ---------------- GEMM1 (K=128, fp32 in) ------------------------------
__global__ __launch_bounds__(256) void k_gemm1(
    const float* __restrict__ X, const unsigned short* __restrict__ Wt,
    unsigned short* __restrict__ out)
{
    __shared__ unsigned short Al[32 * IN_DIM];   // 8 KB
    __shared__ unsigned short Bl[64 * IN_DIM];   // 16 KB
    gemm_body<IN_DIM, false>(Al, Bl, X, Wt, out, blockIdx.x, threadIdx.x);
}

// ---------------- GEMM2 (K=64, bf16 in) -------------------------------
__global__ __launch_bounds__(256) void k_gemm2(
    const unsigned short* __restrict__ X, const unsigned short* __restrict__ Wt,
    unsigned short* __restrict__ out)
{
    __shared__ unsigned short Al[32 * HID_DIM];
    __shared__ unsigned short Bl[64 * HID_DIM];
    gemm_body<HID_DIM, true>(Al, Bl, X, Wt, out, blockIdx.x, threadIdx.x);
}

// ---------------- gather SpMM: bf16 dense [N][64], 8-way unroll -------
// One wave per row, lane = feature dim; 8 accumulators = 8 random 128B
// dense reads in flight. r/e0/e1 wave-uniform (scalar).
template <bool APPLY_RELU, bool OUT_BF16>
__global__ __launch_bounds__(256) void k_gather(
    const int2* __restrict__ offs2, const uint2* __restrict__ pairs,
    const unsigned short* __restrict__ dense, const float* __restrict__ bias,
    void* __restrict__ outp)
{
    int t = threadIdx.x;
    int r = __builtin_amdgcn_readfirstlane(blockIdx.x * 4 + (t >> 6));
    int d = t & 63;
    int2 oe = offs2[r];
    int e0 = oe.x, e1 = oe.y;
    float a[8];
    a[0] = bias[d];
    #pragma unroll
    for (int i = 1; i < 8; ++i) a[i] = 0.f;
    int e = e0;
    for (; e + 8 <= e1; e += 8) {
        uint2 p[8];
        #pragma unroll
        for (int i = 0; i < 8; ++i) p[i] = pairs[e + i];
        unsigned v[8];
        #pragma unroll
        for (int i = 0; i < 8; ++i) v[i] = dense[(size_t)p[i].x * 64u + d];
        #pragma unroll
        for (int i = 0; i < 8; ++i)
            a[i] = fmaf(__uint_as_float(p[i].y), bf2f(v[i]), a[i]);
    }
    if (e + 4 <= e1) {
        uint2 p[4];
        #pragma unroll
        for (int i = 0; i < 4; ++i) p[i] = pairs[e + i];
        unsigned v[4];
        #pragma unroll
        for (int i = 0; i < 4; ++i) v[i] = dense[(size_t)p[i].x * 64u + d];
        #pragma unroll
        for (int i = 0; i < 4; ++i)
            a[i] = fmaf(__uint_as_float(p[i].y), bf2f(v[i]), a[i]);
        e += 4;
    }
    for (; e < e1; ++e) {
        uint2 p = pairs[e];
        a[0] = fmaf(__uint_as_float(p.y),
                    bf2f(dense[(size_t)p.x * 64u + d]), a[0]);
    }
    float acc = ((a[0] + a[1]) + (a[2] + a[3])) +
                ((a[4] + a[5]) + (a[6] + a[7]));
    if (APPLY_RELU) acc = fmaxf(acc, 0.f);
    if (OUT_BF16)
        ((unsigned short*)outp)[(size_t)r * 64 + d] = f2bf(acc);
    else
        ((float*)outp)[(size_t)r * 64 + d] = acc;
}

extern "C" void kernel_launch(void* const* d_in, const int* in_sizes, int n_in,
                              void* d_out, int out_size, void* d_ws, size_t ws_size,
                              hipStream_t stream)
{
    const float* x     = (const float*)d_in[0];
    const int*   erow  = (const int*)d_in[1];
    const int*   ecol  = (const int*)d_in[2];
    const float* eval_ = (const float*)d_in[3];
    const float* W1    = (const float*)d_in[4];
    const float* b1    = (const float*)d_in[5];
    const float* W2    = (const float*)d_in[6];
    const float* b2    = (const float*)d_in[7];
    float* out = (float*)d_out;

    // ws (~30 MB): pairs 8.03MB | bucketed 8.03MB | support bf16 6.4MB |
    // agg1 bf16 6.4MB | Wt1 | Wt2 | bcur | offs2
    uint2* pairs    = (uint2*)d_ws;
    uint2* bucketed = pairs + (size_t)NB * BCAP;
    unsigned short* support = (unsigned short*)(bucketed + (size_t)NB * BCAP);
    unsigned short* agg1 = support + (size_t)N_NODES * 64;
    unsigned short* Wt1 = agg1 + (size_t)N_NODES * 64;
    unsigned short* Wt2 = Wt1 + IN_DIM * HID_DIM;
    int*  bcur  = (int*)(Wt2 + HID_DIM * OUT_DIM);
    int2* offs2 = (int2*)(bcur + NB);          // NB=196 even -> 8B-aligned

    const int row_grid = N_NODES / 4;          // 12500 (gather)

    // 8 dispatches, each at its own best geometry
    k_prep<<<49, 256, 0, stream>>>(W1, Wt1, W2, Wt2, bcur);
    k_bscatter<<<NBLK_E, 256, 0, stream>>>(erow, ecol, eval_, bcur, bucketed);
    k_bfinal<<<NB, 256, 0, stream>>>(bcur, bucketed, pairs, offs2);
    k_gemm1<<<GEMM_GRID, 256, 0, stream>>>(x, Wt1, support);
    k_gather<true, true><<<row_grid, 256, 0, stream>>>(
        offs2, pairs, support, b1, agg1);
    k_gemm2<<<GEMM_GRID, 256, 0, stream>>>(agg1, Wt2, support);
    k_gather<false, false><<<row_grid, 256, 0, stream>>>(
        offs2, pairs, support, b2, out);
}

// Round 16
// 96.678 us; speedup vs baseline: 1.2615x; 1.0225x over previous
//
#include <hip/hip_runtime.h>

// GCN forward on MI355X (gfx950).
// R16: fuse GEMM2 into gather1's epilogue. gemm2 is row-local
// (support2[r] = relu(agg1[r]) @ W2), so k_gather_gemm1 gathers 4 rows
// per wave (8 waves/block, 32 rows/block -> 12504 waves, concurrency
// preserved unlike R14's 391-block collapse), writes the relu'd bf16 rows
// into a swizzled LDS A-tile, and MFMAs against LDS-staged Wt2 — deleting
// the gemm2 dispatch and the 12.8MB agg1 round-trip. 6 dispatches.

#define N_NODES 50000
#define N_EDGES 800000
#define IN_DIM  128
#define HID_DIM 64
#define OUT_DIM 64

#define RB   256                      // rows per bucket (bfinal granularity)
#define NB   ((N_NODES + RB - 1) / RB)            // 196
#define EPB  1024                     // edges per bscatter block
#define NBLK_E ((N_EDGES + EPB - 1) / EPB)        // 782
#define BCAP 5120                     // padded bucket region; E=4081, 16sigma
#define GEMM_GRID ((N_NODES + 31) / 32)           // 1563

typedef __attribute__((ext_vector_type(8))) short bf16x8;
typedef __attribute__((ext_vector_type(4))) float f32x4;

__device__ inline unsigned short f2bf(float x) {   // RNE fp32 -> bf16
    unsigned u = __float_as_uint(x);
    return (unsigned short)((u + 0x7FFFu + ((u >> 16) & 1u)) >> 16);
}
__device__ inline float bf2f(unsigned v) {
    return __uint_as_float(v << 16);
}

// ---------------- prep: weight transpose+bf16 convert, bcur zero ------
__global__ __launch_bounds__(256) void k_prep(
    const float* __restrict__ W1, unsigned short* __restrict__ Wt1,
    const float* __restrict__ W2, unsigned short* __restrict__ Wt2,
    int* __restrict__ bcur)
{
    int b = blockIdx.x, t = threadIdx.x;
    if (b < 32) {                       // IN_DIM*HID_DIM = 8192 = 32*256
        int e = b * 256 + t;
        int c = e / IN_DIM, k = e % IN_DIM;
        Wt1[c * IN_DIM + k] = f2bf(W1[k * HID_DIM + c]);
    } else if (b < 48) {                // HID_DIM*OUT_DIM = 4096 = 16*256
        int e2 = (b - 32) * 256 + t;
        int c = e2 / HID_DIM, k = e2 % HID_DIM;
        Wt2[c * HID_DIM + k] = f2bf(W2[k * OUT_DIM + c]);
    } else {
        if (t < NB) bcur[t] = 0;
    }
}

// ---------------- bscatter: 1024 edges/block, LDS sort, coalesced out -
// word0 = col:16 | rowlow:8 (bits 16-23) | bucket:8 (bits 24-31).
__global__ __launch_bounds__(256) void k_bscatter(
    const int* __restrict__ erow, const int* __restrict__ ecol,
    const float* __restrict__ eval_, int* __restrict__ bcur,
    uint2* __restrict__ bucketed)
{
    __shared__ uint2 sbuf[EPB];         // 8 KB
    __shared__ int lc[NB];
    __shared__ int scr[256];
    __shared__ int lbase[NB];
    int t = threadIdx.x;
    if (t < NB) lc[t] = 0;
    __syncthreads();
    int base = blockIdx.x * EPB;
    int ne = min(EPB, N_EDGES - base);
    int bkt[4], rnk[4];
    unsigned w0v[4], vv[4];
    #pragma unroll
    for (int i = 0; i < 4; ++i) {
        int e = base + i * 256 + t;
        bkt[i] = -1;
        if (e < N_EDGES) {
            unsigned r = (unsigned)erow[e];
            bkt[i] = (int)(r >> 8);
            w0v[i] = (unsigned)ecol[e] | ((r & 255u) << 16) | ((r >> 8) << 24);
            vv[i] = __float_as_uint(eval_[e]);
            rnk[i] = atomicAdd(&lc[bkt[i]], 1);
        }
    }
    __syncthreads();
    int cnt = (t < NB) ? lc[t] : 0;
    scr[t] = cnt;
    __syncthreads();
    #pragma unroll
    for (int off = 1; off < 256; off <<= 1) {
        int add = (t >= off) ? scr[t - off] : 0;
        __syncthreads();
        scr[t] += add;
        __syncthreads();
    }
    int excl = scr[t] - cnt;
    __syncthreads();
    scr[t] = excl;                      // bucket start within sbuf
    if (t < NB) lbase[t] = cnt ? atomicAdd(&bcur[t], cnt) : 0;
    __syncthreads();
    #pragma unroll
    for (int i = 0; i < 4; ++i)
        if (bkt[i] >= 0)
            sbuf[scr[bkt[i]] + rnk[i]] = make_uint2(w0v[i], vv[i]);
    __syncthreads();
    #pragma unroll
    for (int i = 0; i < 4; ++i) {
        int idx = i * 256 + t;
        if (idx < ne) {
            uint2 p = sbuf[idx];
            int bk = (int)(p.x >> 24);
            bucketed[(size_t)bk * BCAP + lbase[bk] + (idx - scr[bk])] = p;
        }
    }
}

// ---------------- bfinal: one block per 256-row bucket ----------------
__global__ __launch_bounds__(256) void k_bfinal(
    const int* __restrict__ bcur, const uint2* __restrict__ bucketed,
    uint2* __restrict__ pairs, int2* __restrict__ offs2)
{
    __shared__ uint2 ebuf[BCAP];        // 40 KB
    __shared__ int rcnt[256];
    __shared__ int rsc[256];
    int t = threadIdx.x, b = blockIdx.x;
    int ne = bcur[b];
    int base0 = b * BCAP;
    rcnt[t] = 0;
    __syncthreads();
    for (int i = t; i < ne; i += 256) {
        uint2 p = bucketed[(size_t)base0 + i];
        ebuf[i] = p;
        atomicAdd(&rcnt[(p.x >> 16) & 255], 1);
    }
    __syncthreads();
    int v = rcnt[t];
    rsc[t] = v;
    __syncthreads();
    #pragma unroll
    for (int off = 1; off < 256; off <<= 1) {
        int add = (t >= off) ? rsc[t - off] : 0;
        __syncthreads();
        rsc[t] += add;
        __syncthreads();
    }
    int start = base0 + rsc[t] - v;
    int gr = (b << 8) + t;
    if (gr < N_NODES) offs2[gr] = make_int2(start, start + v);
    rcnt[t] = start;                    // becomes row cursor
    __syncthreads();
    for (int i = t; i < ne; i += 256) {
        uint2 p = ebuf[i];
        int pos = atomicAdd(&rcnt[(p.x >> 16) & 255], 1);
        pairs[pos] = make_uint2(p.x & 0xFFFFu, p.y);
    }
}

// ---------------- MFMA GEMM body (32 rows/block, 4 waves) -------------
template <int K, bool IN_BF16>
__device__ __forceinline__ void gemm_body(
    unsigned short* __restrict__ Al, unsigned short* __restrict__ Bl,
    const void* __restrict__ Xv, const unsigned short* __restrict__ Wt,
    unsigned short* __restrict__ out, int bid, int t)
{
    int m0 = bid * 32;
    #pragma unroll
    for (int i = 0; i < K / 32; ++i) {
        int u4 = i * 256 + t;                 // uint4 index
        int col = (u4 * 8) / K, k = (u4 * 8) % K;
        uint4 w = ((const uint4*)Wt)[u4];
        int byte = (col * K + k) * 2;
        byte ^= ((col & 7) << 4);
        *(uint4*)((char*)Bl + byte) = w;
    }
    if (IN_BF16) {
        const unsigned short* X = (const unsigned short*)Xv;
        int row = t / (K / 8), k = (t % (K / 8)) * 8;
        int grow = m0 + row;
        uint4 v = make_uint4(0, 0, 0, 0);
        if (grow < N_NODES)
            v = *(const uint4*)(X + (size_t)grow * K + k);
        int byte = (row * K + k) * 2;
        byte ^= ((row & 7) << 4);
        *(uint4*)((char*)Al + byte) = v;
    } else {
        const float* X = (const float*)Xv;
        #pragma unroll
        for (int i = 0; i < K / 64; ++i) {
            int f8 = i * 256 + t;             // 8-float group
            int row = (f8 * 8) / K, k = (f8 * 8) % K;
            int grow = m0 + row;
            float4 xa = make_float4(0.f, 0.f, 0.f, 0.f), xb = xa;
            if (grow < N_NODES) {
                const float4* src = (const float4*)(X + (size_t)grow * K + k);
                xa = src[0];
                xb = src[1];
            }
            uint4 v;
            v.x = (unsigned)f2bf(xa.x) | ((unsigned)f2bf(xa.y) << 16);
            v.y = (unsigned)f2bf(xa.z) | ((unsigned)f2bf(xa.w) << 16);
            v.z = (unsigned)f2bf(xb.x) | ((unsigned)f2bf(xb.y) << 16);
            v.w = (unsigned)f2bf(xb.z) | ((unsigned)f2bf(xb.w) << 16);
            int byte = (row * K + k) * 2;
            byte ^= ((row & 7) << 4);
            *(uint4*)((char*)Al + byte) = v;
        }
    }
    __syncthreads();

    int w = t >> 6, l = t & 63;
    int lr0 = (w & 1) * 16;
    int c0  = (w >> 1) * 32;
    int lrow = lr0 + (l & 15);
    int kb = (l >> 4) * 8;
    int col0 = c0 + (l & 15), col1 = col0 + 16;
    f32x4 acc0 = {0.f, 0.f, 0.f, 0.f}, acc1 = {0.f, 0.f, 0.f, 0.f};
    #pragma unroll
    for (int kc = 0; kc < K / 32; ++kc) {
        int ka = kc * 32 + kb;
        int ab = (lrow * K + ka) * 2;  ab ^= ((lrow & 7) << 4);
        int bb0 = (col0 * K + ka) * 2; bb0 ^= ((col0 & 7) << 4);
        int bb1 = (col1 * K + ka) * 2; bb1 ^= ((col1 & 7) << 4);
        bf16x8 a  = *(const bf16x8*)((const char*)Al + ab);
        bf16x8 b0 = *(const bf16x8*)((const char*)Bl + bb0);
        bf16x8 b1 = *(const bf16x8*)((const char*)Bl + bb1);
        acc0 = __builtin_amdgcn_mfma_f32_16x16x32_bf16(a, b0, acc0, 0, 0, 0);
        acc1 = __builtin_amdgcn_mfma_f32_16x16x32_bf16(a, b1, acc1, 0, 0, 0);
    }
    int grow0 = m0 + lr0 + (l >> 4) * 4;
    #pragma unroll
    for (int j = 0; j < 4; ++j) {
        int gr = grow0 + j;
        if (gr < N_NODES) {
            out[(size_t)gr * 64 + col0] = f2bf(acc0[j]);
            out[(size_t)gr * 64 + col1] = f2bf(acc1[j]);
        }
    }
}

// ---------------- GEMM1 (K=128, fp32 in) ------------------------------
__global__ __launch_bounds__(256) void k_gemm1(
    const float* __restrict__ X, const unsigned short* __restrict__ Wt,
    unsigned short* __restrict__ out)
{
    __shared__ unsigned short Al[32 * IN_DIM];   // 8 KB
    __shared__ unsigned short Bl[64 * IN_DIM];   // 16 KB
    gemm_body<IN_DIM, false>(Al, Bl, X, Wt, out, blockIdx.x, threadIdx.x);
}

// ---------------- fused gather1 + GEMM2 -------------------------------
// 512 thr (8 waves), 32 rows/block (grid 1563 -> 12504 waves). Wave w
// gathers rows w*4..w*4+3 (8-deep unroll as proven), applies b1+relu,
// writes bf16 rows into swizzled LDS A-tile; barrier; 8-wave MFMA
// (wave w: rows (w&1)*16, cols (w>>1)*16) against LDS-staged Wt2 writes
// support2 directly. Numerics identical to agg1-store -> gemm2-load.
__global__ __launch_bounds__(512) void k_gather_gemm1(
    const int2* __restrict__ offs2, const uint2* __restrict__ pairs,
    const unsigned short* __restrict__ dense, const float* __restrict__ b1,
    const unsigned short* __restrict__ Wt2, unsigned short* __restrict__ out)
{
    __shared__ unsigned short Al[32 * 64];   // 4 KB
    __shared__ unsigned short Bl[64 * 64];   // 8 KB
    int t = threadIdx.x;
    int m0 = blockIdx.x * 32;
    // stage Bl (Wt2 bf16 [64][64]) swizzled: 512 uint4s, 1 per thread
    {
        int u4 = t;
        int col = (u4 * 8) / 64, k = (u4 * 8) % 64;
        uint4 wv = ((const uint4*)Wt2)[u4];
        int byte = (col * 64 + k) * 2;
        byte ^= ((col & 7) << 4);
        *(uint4*)((char*)Bl + byte) = wv;
    }
    int w = t >> 6, d = t & 63;
    // gather 4 rows per wave
    #pragma unroll 1
    for (int j = 0; j < 4; ++j) {
        int lr = w * 4 + j;
        int r = __builtin_amdgcn_readfirstlane(m0 + lr);
        float acc = 0.f;
        if (r < N_NODES) {
            int2 oe = offs2[r];
            int e0 = oe.x, e1 = oe.y;
            float a[8];
            a[0] = b1[d];
            #pragma unroll
            for (int i = 1; i < 8; ++i) a[i] = 0.f;
            int e = e0;
            for (; e + 8 <= e1; e += 8) {
                uint2 p[8];
                #pragma unroll
                for (int i = 0; i < 8; ++i) p[i] = pairs[e + i];
                unsigned v[8];
                #pragma unroll
                for (int i = 0; i < 8; ++i) v[i] = dense[(size_t)p[i].x * 64u + d];
                #pragma unroll
                for (int i = 0; i < 8; ++i)
                    a[i] = fmaf(__uint_as_float(p[i].y), bf2f(v[i]), a[i]);
            }
            if (e + 4 <= e1) {
                uint2 p[4];
                #pragma unroll
                for (int i = 0; i < 4; ++i) p[i] = pairs[e + i];
                unsigned v[4];
                #pragma unroll
                for (int i = 0; i < 4; ++i) v[i] = dense[(size_t)p[i].x * 64u + d];
                #pragma unroll
                for (int i = 0; i < 4; ++i)
                    a[i] = fmaf(__uint_as_float(p[i].y), bf2f(v[i]), a[i]);
                e += 4;
            }
            for (; e < e1; ++e) {
                uint2 p = pairs[e];
                a[0] = fmaf(__uint_as_float(p.y),
                            bf2f(dense[(size_t)p.x * 64u + d]), a[0]);
            }
            acc = ((a[0] + a[1]) + (a[2] + a[3])) +
                  ((a[4] + a[5]) + (a[6] + a[7]));
            acc = fmaxf(acc, 0.f);           // relu (layer 1)
        }
        int byte = (lr * 64 + d) * 2;
        byte ^= ((lr & 7) << 4);
        *(unsigned short*)((char*)Al + byte) = f2bf(acc);
    }
    __syncthreads();
    // MFMA: 8 waves cover 32 rows x 64 cols (2 row-tiles x 4 col-tiles)
    int l = t & 63;
    int lr0 = (w & 1) * 16;
    int c0  = (w >> 1) * 16;
    int lrow = lr0 + (l & 15);
    int kb = (l >> 4) * 8;
    int col = c0 + (l & 15);
    f32x4 acc0 = {0.f, 0.f, 0.f, 0.f};
    #pragma unroll
    for (int kc = 0; kc < 2; ++kc) {
        int ka = kc * 32 + kb;
        int ab = (lrow * 64 + ka) * 2; ab ^= ((lrow & 7) << 4);
        int bb = (col * 64 + ka) * 2;  bb ^= ((col & 7) << 4);
        bf16x8 a = *(const bf16x8*)((const char*)Al + ab);
        bf16x8 b = *(const bf16x8*)((const char*)Bl + bb);
        acc0 = __builtin_amdgcn_mfma_f32_16x16x32_bf16(a, b, acc0, 0, 0, 0);
    }
    int grow0 = m0 + lr0 + (l >> 4) * 4;
    #pragma unroll
    for (int j = 0; j < 4; ++j) {
        int gr = grow0 + j;
        if (gr < N_NODES)
            out[(size_t)gr * 64 + col] = f2bf(acc0[j]);
    }
}

// ---------------- gather2: bf16 dense [N][64], 8-way unroll, fp32 out -
__global__ __launch_bounds__(256) void k_gather2(
    const int2* __restrict__ offs2, const uint2* __restrict__ pairs,
    const unsigned short* __restrict__ dense, const float* __restrict__ bias,
    float* __restrict__ outp)
{
    int t = threadIdx.x;
    int r = __builtin_amdgcn_readfirstlane(blockIdx.x * 4 + (t >> 6));
    int d = t & 63;
    int2 oe = offs2[r];
    int e0 = oe.x, e1 = oe.y;
    float a[8];
    a[0] = bias[d];
    #pragma unroll
    for (int i = 1; i < 8; ++i) a[i] = 0.f;
    int e = e0;
    for (; e + 8 <= e1; e += 8) {
        uint2 p[8];
        #pragma unroll
        for (int i = 0; i < 8; ++i) p[i] = pairs[e + i];
        unsigned v[8];
        #pragma unroll
        for (int i = 0; i < 8; ++i) v[i] = dense[(size_t)p[i].x * 64u + d];
        #pragma unroll
        for (int i = 0; i < 8; ++i)
            a[i] = fmaf(__uint_as_float(p[i].y), bf2f(v[i]), a[i]);
    }
    if (e + 4 <= e1) {
        uint2 p[4];
        #pragma unroll
        for (int i = 0; i < 4; ++i) p[i] = pairs[e + i];
        unsigned v[4];
        #pragma unroll
        for (int i = 0; i < 4; ++i) v[i] = dense[(size_t)p[i].x * 64u + d];
        #pragma unroll
        for (int i = 0; i < 4; ++i)
            a[i] = fmaf(__uint_as_float(p[i].y), bf2f(v[i]), a[i]);
        e += 4;
    }
    for (; e < e1; ++e) {
        uint2 p = pairs[e];
        a[0] = fmaf(__uint_as_float(p.y),
                    bf2f(dense[(size_t)p.x * 64u + d]), a[0]);
    }
    float acc = ((a[0] + a[1]) + (a[2] + a[3])) +
                ((a[4] + a[5]) + (a[6] + a[7]));
    outp[(size_t)r * 64 + d] = acc;
}

extern "C" void kernel_launch(void* const* d_in, const int* in_sizes, int n_in,
                              void* d_out, int out_size, void* d_ws, size_t ws_size,
                              hipStream_t stream)
{
    const float* x     = (const float*)d_in[0];
    const int*   erow  = (const int*)d_in[1];
    const int*   ecol  = (const int*)d_in[2];
    const float* eval_ = (const float*)d_in[3];
    const float* W1    = (const float*)d_in[4];
    const float* b1    = (const float*)d_in[5];
    const float* W2    = (const float*)d_in[6];
    const float* b2    = (const float*)d_in[7];
    float* out = (float*)d_out;

    // ws (~23 MB): pairs 8.03MB | bucketed 8.03MB | support bf16 6.4MB |
    // Wt1 | Wt2 | bcur | offs2   (agg1 eliminated by the fusion)
    uint2* pairs    = (uint2*)d_ws;
    uint2* bucketed = pairs + (size_t)NB * BCAP;
    unsigned short* support = (unsigned short*)(bucketed + (size_t)NB * BCAP);
    unsigned short* Wt1 = support + (size_t)N_NODES * 64;
    unsigned short* Wt2 = Wt1 + IN_DIM * HID_DIM;
    int*  bcur  = (int*)(Wt2 + HID_DIM * OUT_DIM);
    int2* offs2 = (int2*)(bcur + NB);          // NB=196 even -> 8B-aligned

    // support2 reuses... needs its own buffer: place after offs2
    unsigned short* support2 = (unsigned short*)(offs2 + N_NODES + 2);

    const int row_grid = N_NODES / 4;          // 12500 (gather2)

    // 6 dispatches
    k_prep<<<49, 256, 0, stream>>>(W1, Wt1, W2, Wt2, bcur);
    k_bscatter<<<NBLK_E, 256, 0, stream>>>(erow, ecol, eval_, bcur, bucketed);
    k_bfinal<<<NB, 256, 0, stream>>>(bcur, bucketed, pairs, offs2);
    k_gemm1<<<GEMM_GRID, 256, 0, stream>>>(x, Wt1, support);
    k_gather_gemm1<<<GEMM_GRID, 512, 0, stream>>>(
        offs2, pairs, support, b1, Wt2, support2);
    k_gather2<<<row_grid, 256, 0, stream>>>(
        offs2, pairs, support2, b2, out);
}

// Round 17
// 94.743 us; speedup vs baseline: 1.2873x; 1.0204x over previous
//
#include <hip/hip_runtime.h>

// GCN forward on MI355X (gfx950).
// R17: (1) bscatter || gemm1 truly overlapped — bscatter blocks FIRST in
// the merged dispatch (in-order block launch starts them immediately, the
// 1563 gemm blocks fill behind); lean 24KB LDS union. (2) bfinal split
// into 392 half-bucket blocks (was 196 = 0.77/CU): two passes over the
// L2-hot bucket instead of a 40KB LDS cache, 1KB LDS. (3) gather2 gets a
// 16-deep unroll tier (mean degree 16 -> one latency batch). 5 dispatches.

#define N_NODES 50000
#define N_EDGES 800000
#define IN_DIM  128
#define HID_DIM 64
#define OUT_DIM 64

#define RB   256                      // rows per bucket
#define NB   ((N_NODES + RB - 1) / RB)            // 196
#define EPB  1024                     // edges per bscatter block
#define NBLK_E ((N_EDGES + EPB - 1) / EPB)        // 782
#define BCAP 5120                     // padded bucket region; E=4081, 16sigma
#define GEMM_GRID ((N_NODES + 31) / 32)           // 1563

typedef __attribute__((ext_vector_type(8))) short bf16x8;
typedef __attribute__((ext_vector_type(4))) float f32x4;

__device__ inline unsigned short f2bf(float x) {   // RNE fp32 -> bf16
    unsigned u = __float_as_uint(x);
    return (unsigned short)((u + 0x7FFFu + ((u >> 16) & 1u)) >> 16);
}
__device__ inline float bf2f(unsigned v) {
    return __uint_as_float(v << 16);
}

// ---------------- prep: weight transpose+bf16 convert, bcur zero ------
__global__ __launch_bounds__(256) void k_prep(
    const float* __restrict__ W1, unsigned short* __restrict__ Wt1,
    const float* __restrict__ W2, unsigned short* __restrict__ Wt2,
    int* __restrict__ bcur)
{
    int b = blockIdx.x, t = threadIdx.x;
    if (b < 32) {                       // IN_DIM*HID_DIM = 8192 = 32*256
        int e = b * 256 + t;
        int c = e / IN_DIM, k = e % IN_DIM;
        Wt1[c * IN_DIM + k] = f2bf(W1[k * HID_DIM + c]);
    } else if (b < 48) {                // HID_DIM*OUT_DIM = 4096 = 16*256
        int e2 = (b - 32) * 256 + t;
        int c = e2 / HID_DIM, k = e2 % HID_DIM;
        Wt2[c * HID_DIM + k] = f2bf(W2[k * OUT_DIM + c]);
    } else {
        if (t < NB) bcur[t] = 0;
    }
}

// ---------------- MFMA GEMM body (32 rows/block, 4 waves) -------------
template <int K, bool IN_BF16>
__device__ __forceinline__ void gemm_body(
    unsigned short* __restrict__ Al, unsigned short* __restrict__ Bl,
    const void* __restrict__ Xv, const unsigned short* __restrict__ Wt,
    unsigned short* __restrict__ out, int bid, int t)
{
    int m0 = bid * 32;
    #pragma unroll
    for (int i = 0; i < K / 32; ++i) {
        int u4 = i * 256 + t;                 // uint4 index
        int col = (u4 * 8) / K, k = (u4 * 8) % K;
        uint4 w = ((const uint4*)Wt)[u4];
        int byte = (col * K + k) * 2;
        byte ^= ((col & 7) << 4);
        *(uint4*)((char*)Bl + byte) = w;
    }
    if (IN_BF16) {
        const unsigned short* X = (const unsigned short*)Xv;
        int row = t / (K / 8), k = (t % (K / 8)) * 8;
        int grow = m0 + row;
        uint4 v = make_uint4(0, 0, 0, 0);
        if (grow < N_NODES)
            v = *(const uint4*)(X + (size_t)grow * K + k);
        int byte = (row * K + k) * 2;
        byte ^= ((row & 7) << 4);
        *(uint4*)((char*)Al + byte) = v;
    } else {
        const float* X = (const float*)Xv;
        #pragma unroll
        for (int i = 0; i < K / 64; ++i) {
            int f8 = i * 256 + t;             // 8-float group
            int row = (f8 * 8) / K, k = (f8 * 8) % K;
            int grow = m0 + row;
            float4 xa = make_float4(0.f, 0.f, 0.f, 0.f), xb = xa;
            if (grow < N_NODES) {
                const float4* src = (const float4*)(X + (size_t)grow * K + k);
                xa = src[0];
                xb = src[1];
            }
            uint4 v;
            v.x = (unsigned)f2bf(xa.x) | ((unsigned)f2bf(xa.y) << 16);
            v.y = (unsigned)f2bf(xa.z) | ((unsigned)f2bf(xa.w) << 16);
            v.z = (unsigned)f2bf(xb.x) | ((unsigned)f2bf(xb.y) << 16);
            v.w = (unsigned)f2bf(xb.z) | ((unsigned)f2bf(xb.w) << 16);
            int byte = (row * K + k) * 2;
            byte ^= ((row & 7) << 4);
            *(uint4*)((char*)Al + byte) = v;
        }
    }
    __syncthreads();

    int w = t >> 6, l = t & 63;
    int lr0 = (w & 1) * 16;
    int c0  = (w >> 1) * 32;
    int lrow = lr0 + (l & 15);
    int kb = (l >> 4) * 8;
    int col0 = c0 + (l & 15), col1 = col0 + 16;
    f32x4 acc0 = {0.f, 0.f, 0.f, 0.f}, acc1 = {0.f, 0.f, 0.f, 0.f};
    #pragma unroll
    for (int kc = 0; kc < K / 32; ++kc) {
        int ka = kc * 32 + kb;
        int ab = (lrow * K + ka) * 2;  ab ^= ((lrow & 7) << 4);
        int bb0 = (col0 * K + ka) * 2; bb0 ^= ((col0 & 7) << 4);
        int bb1 = (col1 * K + ka) * 2; bb1 ^= ((col1 & 7) << 4);
        bf16x8 a  = *(const bf16x8*)((const char*)Al + ab);
        bf16x8 b0 = *(const bf16x8*)((const char*)Bl + bb0);
        bf16x8 b1 = *(const bf16x8*)((const char*)Bl + bb1);
        acc0 = __builtin_amdgcn_mfma_f32_16x16x32_bf16(a, b0, acc0, 0, 0, 0);
        acc1 = __builtin_amdgcn_mfma_f32_16x16x32_bf16(a, b1, acc1, 0, 0, 0);
    }
    int grow0 = m0 + lr0 + (l >> 4) * 4;
    #pragma unroll
    for (int j = 0; j < 4; ++j) {
        int gr = grow0 + j;
        if (gr < N_NODES) {
            out[(size_t)gr * 64 + col0] = f2bf(acc0[j]);
            out[(size_t)gr * 64 + col1] = f2bf(acc1[j]);
        }
    }
}

// ---------------- mega: bscatter (blocks [0,782)) || GEMM1 ------------
// bscatter FIRST so it starts immediately; gemm1 blocks fill behind.
// bscatter: LDS bucket-sort then coalesced writeout (R15-proven).
// word0 = col:16 | rowlow:8 (bits 16-23) | bucket:8 (bits 24-31).
__global__ __launch_bounds__(256) void k_mega(
    const int* __restrict__ erow, const int* __restrict__ ecol,
    const float* __restrict__ eval_, int* __restrict__ bcur,
    uint2* __restrict__ bucketed,
    const float* __restrict__ X, const unsigned short* __restrict__ Wt1,
    unsigned short* __restrict__ support)
{
    __shared__ __align__(16) unsigned char smem[24576];
    int t = threadIdx.x;
    if (blockIdx.x >= NBLK_E) {
        gemm_body<IN_DIM, false>((unsigned short*)smem,
                                 (unsigned short*)(smem + 8192),
                                 X, Wt1, support, blockIdx.x - NBLK_E, t);
        return;
    }
    uint2* sbuf  = (uint2*)smem;                 // 8 KB (1024 edges)
    int*   lc    = (int*)(smem + 8192);
    int*   scr   = lc + 256;
    int*   lbase = scr + 256;
    if (t < NB) lc[t] = 0;
    __syncthreads();
    int base = blockIdx.x * EPB;
    int ne = min(EPB, N_EDGES - base);
    int bkt[4], rnk[4];
    unsigned w0v[4], vv[4];
    #pragma unroll
    for (int i = 0; i < 4; ++i) {
        int e = base + i * 256 + t;
        bkt[i] = -1;
        if (e < N_EDGES) {
            unsigned r = (unsigned)erow[e];
            bkt[i] = (int)(r >> 8);
            w0v[i] = (unsigned)ecol[e] | ((r & 255u) << 16) | ((r >> 8) << 24);
            vv[i] = __float_as_uint(eval_[e]);
            rnk[i] = atomicAdd(&lc[bkt[i]], 1);
        }
    }
    __syncthreads();
    int cnt = (t < NB) ? lc[t] : 0;
    scr[t] = cnt;
    __syncthreads();
    #pragma unroll
    for (int off = 1; off < 256; off <<= 1) {
        int add = (t >= off) ? scr[t - off] : 0;
        __syncthreads();
        scr[t] += add;
        __syncthreads();
    }
    int excl = scr[t] - cnt;
    __syncthreads();
    scr[t] = excl;                      // bucket start within sbuf
    if (t < NB) lbase[t] = cnt ? atomicAdd(&bcur[t], cnt) : 0;
    __syncthreads();
    #pragma unroll
    for (int i = 0; i < 4; ++i)
        if (bkt[i] >= 0)
            sbuf[scr[bkt[i]] + rnk[i]] = make_uint2(w0v[i], vv[i]);
    __syncthreads();
    #pragma unroll
    for (int i = 0; i < 4; ++i) {
        int idx = i * 256 + t;
        if (idx < ne) {
            uint2 p = sbuf[idx];
            int bk = (int)(p.x >> 24);
            bucketed[(size_t)bk * BCAP + lbase[bk] + (idx - scr[bk])] = p;
        }
    }
}

// ---------------- bfinal2: 2 blocks per bucket (392 blocks) -----------
// Block handles rows [B*256 + h*128, +128). Two passes over the bucket's
// edges (L2-hot 32KB): count kept -> wave-0 scan -> offs2 -> scatter.
// 1KB LDS -> high occupancy.
__global__ __launch_bounds__(256) void k_bfinal2(
    const int* __restrict__ bcur, const uint2* __restrict__ bucketed,
    uint2* __restrict__ pairs, int2* __restrict__ offs2)
{
    __shared__ int rcnt[128], rst[128];
    __shared__ int nkept_sh;
    int t = threadIdx.x, blk = blockIdx.x;
    int B = blk >> 1, h = blk & 1;
    int ne = bcur[B];
    size_t eb = (size_t)B * BCAP;
    if (t < 128) rcnt[t] = 0;
    __syncthreads();
    // pass 1: count this half's edges
    for (int i = t; i < ne; i += 256) {
        unsigned w0 = bucketed[eb + i].x;
        int rl = (int)((w0 >> 16) & 255u);
        if ((rl >> 7) == h) atomicAdd(&rcnt[rl & 127], 1);
    }
    __syncthreads();
    if (t < 64) {                       // wave-0 scan of 128 counts
        int c0 = rcnt[2 * t], c1 = rcnt[2 * t + 1];
        int s = c0 + c1, inc = s;
        #pragma unroll
        for (int off = 1; off < 64; off <<= 1) {
            int o = __shfl_up(inc, off, 64);
            if (t >= off) inc += o;
        }
        int excl = inc - s;
        int tot = __shfl(inc, 63, 64);
        if (t == 0) nkept_sh = tot;
        rst[2 * t] = excl;
        rst[2 * t + 1] = excl + c0;
    }
    __syncthreads();
    int nk = nkept_sh;
    int regionBase = (int)eb + (h ? (ne - nk) : 0);
    if (t < 128) {
        int gr = B * 256 + h * 128 + t;
        int st = regionBase + rst[t];
        if (gr < N_NODES) offs2[gr] = make_int2(st, st + rcnt[t]);
        rst[t] = st;                    // becomes row cursor
    }
    __syncthreads();
    // pass 2: scatter kept edges row-sorted into pairs
    for (int i = t; i < ne; i += 256) {
        uint2 p = bucketed[eb + i];
        int rl = (int)((p.x >> 16) & 255u);
        if ((rl >> 7) == h) {
            int pos = atomicAdd(&rst[rl & 127], 1);
            pairs[pos] = make_uint2(p.x & 0xFFFFu, p.y);
        }
    }
}

// ---------------- fused gather1 + GEMM2 (R16-proven) ------------------
__global__ __launch_bounds__(512) void k_gather_gemm1(
    const int2* __restrict__ offs2, const uint2* __restrict__ pairs,
    const unsigned short* __restrict__ dense, const float* __restrict__ b1,
    const unsigned short* __restrict__ Wt2, unsigned short* __restrict__ out)
{
    __shared__ unsigned short Al[32 * 64];   // 4 KB
    __shared__ unsigned short Bl[64 * 64];   // 8 KB
    int t = threadIdx.x;
    int m0 = blockIdx.x * 32;
    {
        int u4 = t;
        int col = (u4 * 8) / 64, k = (u4 * 8) % 64;
        uint4 wv = ((const uint4*)Wt2)[u4];
        int byte = (col * 64 + k) * 2;
        byte ^= ((col & 7) << 4);
        *(uint4*)((char*)Bl + byte) = wv;
    }
    int w = t >> 6, d = t & 63;
    #pragma unroll 1
    for (int j = 0; j < 4; ++j) {
        int lr = w * 4 + j;
        int r = __builtin_amdgcn_readfirstlane(m0 + lr);
        float acc = 0.f;
        if (r < N_NODES) {
            int2 oe = offs2[r];
            int e0 = oe.x, e1 = oe.y;
            float a[8];
            a[0] = b1[d];
            #pragma unroll
            for (int i = 1; i < 8; ++i) a[i] = 0.f;
            int e = e0;
            for (; e + 8 <= e1; e += 8) {
                uint2 p[8];
                #pragma unroll
                for (int i = 0; i < 8; ++i) p[i] = pairs[e + i];
                unsigned v[8];
                #pragma unroll
                for (int i = 0; i < 8; ++i) v[i] = dense[(size_t)p[i].x * 64u + d];
                #pragma unroll
                for (int i = 0; i < 8; ++i)
                    a[i] = fmaf(__uint_as_float(p[i].y), bf2f(v[i]), a[i]);
            }
            if (e + 4 <= e1) {
                uint2 p[4];
                #pragma unroll
                for (int i = 0; i < 4; ++i) p[i] = pairs[e + i];
                unsigned v[4];
                #pragma unroll
                for (int i = 0; i < 4; ++i) v[i] = dense[(size_t)p[i].x * 64u + d];
                #pragma unroll
                for (int i = 0; i < 4; ++i)
                    a[i] = fmaf(__uint_as_float(p[i].y), bf2f(v[i]), a[i]);
                e += 4;
            }
            for (; e < e1; ++e) {
                uint2 p = pairs[e];
                a[0] = fmaf(__uint_as_float(p.y),
                            bf2f(dense[(size_t)p.x * 64u + d]), a[0]);
            }
            acc = ((a[0] + a[1]) + (a[2] + a[3])) +
                  ((a[4] + a[5]) + (a[6] + a[7]));
            acc = fmaxf(acc, 0.f);           // relu (layer 1)
        }
        int byte = (lr * 64 + d) * 2;
        byte ^= ((lr & 7) << 4);
        *(unsigned short*)((char*)Al + byte) = f2bf(acc);
    }
    __syncthreads();
    int l = t & 63;
    int lr0 = (w & 1) * 16;
    int c0  = (w >> 1) * 16;
    int lrow = lr0 + (l & 15);
    int kb = (l >> 4) * 8;
    int col = c0 + (l & 15);
    f32x4 acc0 = {0.f, 0.f, 0.f, 0.f};
    #pragma unroll
    for (int kc = 0; kc < 2; ++kc) {
        int ka = kc * 32 + kb;
        int ab = (lrow * 64 + ka) * 2; ab ^= ((lrow & 7) << 4);
        int bb = (col * 64 + ka) * 2;  bb ^= ((col & 7) << 4);
        bf16x8 a = *(const bf16x8*)((const char*)Al + ab);
        bf16x8 b = *(const bf16x8*)((const char*)Bl + bb);
        acc0 = __builtin_amdgcn_mfma_f32_16x16x32_bf16(a, b, acc0, 0, 0, 0);
    }
    int grow0 = m0 + lr0 + (l >> 4) * 4;
    #pragma unroll
    for (int j = 0; j < 4; ++j) {
        int gr = grow0 + j;
        if (gr < N_NODES)
            out[(size_t)gr * 64 + col] = f2bf(acc0[j]);
    }
}

// ---------------- gather2: 16-deep unroll, fp32 out -------------------
__global__ __launch_bounds__(256) void k_gather2(
    const int2* __restrict__ offs2, const uint2* __restrict__ pairs,
    const unsigned short* __restrict__ dense, const float* __restrict__ bias,
    float* __restrict__ outp)
{
    int t = threadIdx.x;
    int r = __builtin_amdgcn_readfirstlane(blockIdx.x * 4 + (t >> 6));
    int d = t & 63;
    int2 oe = offs2[r];
    int e0 = oe.x, e1 = oe.y;
    float a[16];
    a[0] = bias[d];
    #pragma unroll
    for (int i = 1; i < 16; ++i) a[i] = 0.f;
    int e = e0;
    for (; e + 16 <= e1; e += 16) {      // mean degree 16 -> one batch
        uint2 p[16];
        #pragma unroll
        for (int i = 0; i < 16; ++i) p[i] = pairs[e + i];
        unsigned v[16];
        #pragma unroll
        for (int i = 0; i < 16; ++i) v[i] = dense[(size_t)p[i].x * 64u + d];
        #pragma unroll
        for (int i = 0; i < 16; ++i)
            a[i] = fmaf(__uint_as_float(p[i].y), bf2f(v[i]), a[i]);
    }
    if (e + 8 <= e1) {
        uint2 p[8];
        #pragma unroll
        for (int i = 0; i < 8; ++i) p[i] = pairs[e + i];
        unsigned v[8];
        #pragma unroll
        for (int i = 0; i < 8; ++i) v[i] = dense[(size_t)p[i].x * 64u + d];
        #pragma unroll
        for (int i = 0; i < 8; ++i)
            a[i] = fmaf(__uint_as_float(p[i].y), bf2f(v[i]), a[i]);
        e += 8;
    }
    if (e + 4 <= e1) {
        uint2 p[4];
        #pragma unroll
        for (int i = 0; i < 4; ++i) p[i] = pairs[e + i];
        unsigned v[4];
        #pragma unroll
        for (int i = 0; i < 4; ++i) v[i] = dense[(size_t)p[i].x * 64u + d];
        #pragma unroll
        for (int i = 0; i < 4; ++i)
            a[i] = fmaf(__uint_as_float(p[i].y), bf2f(v[i]), a[i]);
        e += 4;
    }
    for (; e < e1; ++e) {
        uint2 p = pairs[e];
        a[0] = fmaf(__uint_as_float(p.y),
                    bf2f(dense[(size_t)p.x * 64u + d]), a[0]);
    }
    float s0 = ((a[0] + a[1]) + (a[2] + a[3])) +
               ((a[4] + a[5]) + (a[6] + a[7]));
    float s1 = ((a[8] + a[9]) + (a[10] + a[11])) +
               ((a[12] + a[13]) + (a[14] + a[15]));
    outp[(size_t)r * 64 + d] = s0 + s1;
}

extern "C" void kernel_launch(void* const* d_in, const int* in_sizes, int n_in,
                              void* d_out, int out_size, void* d_ws, size_t ws_size,
                              hipStream_t stream)
{
    const float* x     = (const float*)d_in[0];
    const int*   erow  = (const int*)d_in[1];
    const int*   ecol  = (const int*)d_in[2];
    const float* eval_ = (const float*)d_in[3];
    const float* W1    = (const float*)d_in[4];
    const float* b1    = (const float*)d_in[5];
    const float* W2    = (const float*)d_in[6];
    const float* b2    = (const float*)d_in[7];
    float* out = (float*)d_out;

    // ws (~30 MB): pairs 8.03MB | bucketed 8.03MB | support bf16 6.4MB |
    // Wt1 | Wt2 | bcur | offs2 | support2 bf16 6.4MB
    uint2* pairs    = (uint2*)d_ws;
    uint2* bucketed = pairs + (size_t)NB * BCAP;
    unsigned short* support = (unsigned short*)(bucketed + (size_t)NB * BCAP);
    unsigned short* Wt1 = support + (size_t)N_NODES * 64;
    unsigned short* Wt2 = Wt1 + IN_DIM * HID_DIM;
    int*  bcur  = (int*)(Wt2 + HID_DIM * OUT_DIM);
    int2* offs2 = (int2*)(bcur + NB);          // NB=196 even -> 8B-aligned
    unsigned short* support2 = (unsigned short*)(offs2 + N_NODES + 2);

    const int row_grid = N_NODES / 4;          // 12500 (gather2)

    // 5 dispatches
    k_prep<<<49, 256, 0, stream>>>(W1, Wt1, W2, Wt2, bcur);
    k_mega<<<NBLK_E + GEMM_GRID, 256, 0, stream>>>(
        erow, ecol, eval_, bcur, bucketed, x, Wt1, support);
    k_bfinal2<<<2 * NB, 256, 0, stream>>>(bcur, bucketed, pairs, offs2);
    k_gather_gemm1<<<GEMM_GRID, 512, 0, stream>>>(
        offs2, pairs, support, b1, Wt2, support2);
    k_gather2<<<row_grid, 256, 0, stream>>>(
        offs2, pairs, support2, b2, out);
}

// Round 18
// 94.123 us; speedup vs baseline: 1.2958x; 1.0066x over previous
//
#include <hip/hip_runtime.h>

// GCN forward on MI355X (gfx950).
// R18: persistent gathers. Gathers are concurrency-bound (MLP scaling
// proved it: 4->8-way unroll halved them) but occupancy reads only ~63%
// — block drain/refill churn from 12500 short blocks. Fix: launch exactly
// resident capacity and grid-stride (blocks live the whole phase).
// gather_gemm1 also hoists Wt2 LDS staging to once per block. 5 dispatches.

#define N_NODES 50000
#define N_EDGES 800000
#define IN_DIM  128
#define HID_DIM 64
#define OUT_DIM 64

#define RB   256                      // rows per bucket
#define NB   ((N_NODES + RB - 1) / RB)            // 196
#define EPB  1024                     // edges per bscatter block
#define NBLK_E ((N_EDGES + EPB - 1) / EPB)        // 782
#define BCAP 5120                     // padded bucket region; E=4081, 16sigma
#define GEMM_GRID ((N_NODES + 31) / 32)           // 1563
#define G2_TILES (N_NODES / 4)                    // 12500 gather2 row-tiles
#define PERSIST2 2048                 // gather2 persistent blocks (8/CU)
#define PERSIST1 1024                 // gather_gemm1 persistent blocks (4/CU)

typedef __attribute__((ext_vector_type(8))) short bf16x8;
typedef __attribute__((ext_vector_type(4))) float f32x4;

__device__ inline unsigned short f2bf(float x) {   // RNE fp32 -> bf16
    unsigned u = __float_as_uint(x);
    return (unsigned short)((u + 0x7FFFu + ((u >> 16) & 1u)) >> 16);
}
__device__ inline float bf2f(unsigned v) {
    return __uint_as_float(v << 16);
}

// ---------------- prep: weight transpose+bf16 convert, bcur zero ------
__global__ __launch_bounds__(256) void k_prep(
    const float* __restrict__ W1, unsigned short* __restrict__ Wt1,
    const float* __restrict__ W2, unsigned short* __restrict__ Wt2,
    int* __restrict__ bcur)
{
    int b = blockIdx.x, t = threadIdx.x;
    if (b < 32) {                       // IN_DIM*HID_DIM = 8192 = 32*256
        int e = b * 256 + t;
        int c = e / IN_DIM, k = e % IN_DIM;
        Wt1[c * IN_DIM + k] = f2bf(W1[k * HID_DIM + c]);
    } else if (b < 48) {                // HID_DIM*OUT_DIM = 4096 = 16*256
        int e2 = (b - 32) * 256 + t;
        int c = e2 / HID_DIM, k = e2 % HID_DIM;
        Wt2[c * HID_DIM + k] = f2bf(W2[k * OUT_DIM + c]);
    } else {
        if (t < NB) bcur[t] = 0;
    }
}

// ---------------- MFMA GEMM body (32 rows/block, 4 waves) -------------
template <int K, bool IN_BF16>
__device__ __forceinline__ void gemm_body(
    unsigned short* __restrict__ Al, unsigned short* __restrict__ Bl,
    const void* __restrict__ Xv, const unsigned short* __restrict__ Wt,
    unsigned short* __restrict__ out, int bid, int t)
{
    int m0 = bid * 32;
    #pragma unroll
    for (int i = 0; i < K / 32; ++i) {
        int u4 = i * 256 + t;                 // uint4 index
        int col = (u4 * 8) / K, k = (u4 * 8) % K;
        uint4 w = ((const uint4*)Wt)[u4];
        int byte = (col * K + k) * 2;
        byte ^= ((col & 7) << 4);
        *(uint4*)((char*)Bl + byte) = w;
    }
    if (IN_BF16) {
        const unsigned short* X = (const unsigned short*)Xv;
        int row = t / (K / 8), k = (t % (K / 8)) * 8;
        int grow = m0 + row;
        uint4 v = make_uint4(0, 0, 0, 0);
        if (grow < N_NODES)
            v = *(const uint4*)(X + (size_t)grow * K + k);
        int byte = (row * K + k) * 2;
        byte ^= ((row & 7) << 4);
        *(uint4*)((char*)Al + byte) = v;
    } else {
        const float* X = (const float*)Xv;
        #pragma unroll
        for (int i = 0; i < K / 64; ++i) {
            int f8 = i * 256 + t;             // 8-float group
            int row = (f8 * 8) / K, k = (f8 * 8) % K;
            int grow = m0 + row;
            float4 xa = make_float4(0.f, 0.f, 0.f, 0.f), xb = xa;
            if (grow < N_NODES) {
                const float4* src = (const float4*)(X + (size_t)grow * K + k);
                xa = src[0];
                xb = src[1];
            }
            uint4 v;
            v.x = (unsigned)f2bf(xa.x) | ((unsigned)f2bf(xa.y) << 16);
            v.y = (unsigned)f2bf(xa.z) | ((unsigned)f2bf(xa.w) << 16);
            v.z = (unsigned)f2bf(xb.x) | ((unsigned)f2bf(xb.y) << 16);
            v.w = (unsigned)f2bf(xb.z) | ((unsigned)f2bf(xb.w) << 16);
            int byte = (row * K + k) * 2;
            byte ^= ((row & 7) << 4);
            *(uint4*)((char*)Al + byte) = v;
        }
    }
    __syncthreads();

    int w = t >> 6, l = t & 63;
    int lr0 = (w & 1) * 16;
    int c0  = (w >> 1) * 32;
    int lrow = lr0 + (l & 15);
    int kb = (l >> 4) * 8;
    int col0 = c0 + (l & 15), col1 = col0 + 16;
    f32x4 acc0 = {0.f, 0.f, 0.f, 0.f}, acc1 = {0.f, 0.f, 0.f, 0.f};
    #pragma unroll
    for (int kc = 0; kc < K / 32; ++kc) {
        int ka = kc * 32 + kb;
        int ab = (lrow * K + ka) * 2;  ab ^= ((lrow & 7) << 4);
        int bb0 = (col0 * K + ka) * 2; bb0 ^= ((col0 & 7) << 4);
        int bb1 = (col1 * K + ka) * 2; bb1 ^= ((col1 & 7) << 4);
        bf16x8 a  = *(const bf16x8*)((const char*)Al + ab);
        bf16x8 b0 = *(const bf16x8*)((const char*)Bl + bb0);
        bf16x8 b1 = *(const bf16x8*)((const char*)Bl + bb1);
        acc0 = __builtin_amdgcn_mfma_f32_16x16x32_bf16(a, b0, acc0, 0, 0, 0);
        acc1 = __builtin_amdgcn_mfma_f32_16x16x32_bf16(a, b1, acc1, 0, 0, 0);
    }
    int grow0 = m0 + lr0 + (l >> 4) * 4;
    #pragma unroll
    for (int j = 0; j < 4; ++j) {
        int gr = grow0 + j;
        if (gr < N_NODES) {
            out[(size_t)gr * 64 + col0] = f2bf(acc0[j]);
            out[(size_t)gr * 64 + col1] = f2bf(acc1[j]);
        }
    }
}

// ---------------- mega: bscatter (blocks [0,782)) || GEMM1 ------------
__global__ __launch_bounds__(256) void k_mega(
    const int* __restrict__ erow, const int* __restrict__ ecol,
    const float* __restrict__ eval_, int* __restrict__ bcur,
    uint2* __restrict__ bucketed,
    const float* __restrict__ X, const unsigned short* __restrict__ Wt1,
    unsigned short* __restrict__ support)
{
    __shared__ __align__(16) unsigned char smem[24576];
    int t = threadIdx.x;
    if (blockIdx.x >= NBLK_E) {
        gemm_body<IN_DIM, false>((unsigned short*)smem,
                                 (unsigned short*)(smem + 8192),
                                 X, Wt1, support, blockIdx.x - NBLK_E, t);
        return;
    }
    uint2* sbuf  = (uint2*)smem;                 // 8 KB (1024 edges)
    int*   lc    = (int*)(smem + 8192);
    int*   scr   = lc + 256;
    int*   lbase = scr + 256;
    if (t < NB) lc[t] = 0;
    __syncthreads();
    int base = blockIdx.x * EPB;
    int ne = min(EPB, N_EDGES - base);
    int bkt[4], rnk[4];
    unsigned w0v[4], vv[4];
    #pragma unroll
    for (int i = 0; i < 4; ++i) {
        int e = base + i * 256 + t;
        bkt[i] = -1;
        if (e < N_EDGES) {
            unsigned r = (unsigned)erow[e];
            bkt[i] = (int)(r >> 8);
            w0v[i] = (unsigned)ecol[e] | ((r & 255u) << 16) | ((r >> 8) << 24);
            vv[i] = __float_as_uint(eval_[e]);
            rnk[i] = atomicAdd(&lc[bkt[i]], 1);
        }
    }
    __syncthreads();
    int cnt = (t < NB) ? lc[t] : 0;
    scr[t] = cnt;
    __syncthreads();
    #pragma unroll
    for (int off = 1; off < 256; off <<= 1) {
        int add = (t >= off) ? scr[t - off] : 0;
        __syncthreads();
        scr[t] += add;
        __syncthreads();
    }
    int excl = scr[t] - cnt;
    __syncthreads();
    scr[t] = excl;                      // bucket start within sbuf
    if (t < NB) lbase[t] = cnt ? atomicAdd(&bcur[t], cnt) : 0;
    __syncthreads();
    #pragma unroll
    for (int i = 0; i < 4; ++i)
        if (bkt[i] >= 0)
            sbuf[scr[bkt[i]] + rnk[i]] = make_uint2(w0v[i], vv[i]);
    __syncthreads();
    #pragma unroll
    for (int i = 0; i < 4; ++i) {
        int idx = i * 256 + t;
        if (idx < ne) {
            uint2 p = sbuf[idx];
            int bk = (int)(p.x >> 24);
            bucketed[(size_t)bk * BCAP + lbase[bk] + (idx - scr[bk])] = p;
        }
    }
}

// ---------------- bfinal2: 2 blocks per bucket (392 blocks) -----------
__global__ __launch_bounds__(256) void k_bfinal2(
    const int* __restrict__ bcur, const uint2* __restrict__ bucketed,
    uint2* __restrict__ pairs, int2* __restrict__ offs2)
{
    __shared__ int rcnt[128], rst[128];
    __shared__ int nkept_sh;
    int t = threadIdx.x, blk = blockIdx.x;
    int B = blk >> 1, h = blk & 1;
    int ne = bcur[B];
    size_t eb = (size_t)B * BCAP;
    if (t < 128) rcnt[t] = 0;
    __syncthreads();
    for (int i = t; i < ne; i += 256) {
        unsigned w0 = bucketed[eb + i].x;
        int rl = (int)((w0 >> 16) & 255u);
        if ((rl >> 7) == h) atomicAdd(&rcnt[rl & 127], 1);
    }
    __syncthreads();
    if (t < 64) {                       // wave-0 scan of 128 counts
        int c0 = rcnt[2 * t], c1 = rcnt[2 * t + 1];
        int s = c0 + c1, inc = s;
        #pragma unroll
        for (int off = 1; off < 64; off <<= 1) {
            int o = __shfl_up(inc, off, 64);
            if (t >= off) inc += o;
        }
        int excl = inc - s;
        int tot = __shfl(inc, 63, 64);
        if (t == 0) nkept_sh = tot;
        rst[2 * t] = excl;
        rst[2 * t + 1] = excl + c0;
    }
    __syncthreads();
    int nk = nkept_sh;
    int regionBase = (int)eb + (h ? (ne - nk) : 0);
    if (t < 128) {
        int gr = B * 256 + h * 128 + t;
        int st = regionBase + rst[t];
        if (gr < N_NODES) offs2[gr] = make_int2(st, st + rcnt[t]);
        rst[t] = st;                    // becomes row cursor
    }
    __syncthreads();
    for (int i = t; i < ne; i += 256) {
        uint2 p = bucketed[eb + i];
        int rl = (int)((p.x >> 16) & 255u);
        if ((rl >> 7) == h) {
            int pos = atomicAdd(&rst[rl & 127], 1);
            pairs[pos] = make_uint2(p.x & 0xFFFFu, p.y);
        }
    }
}

// ---------------- fused gather1 + GEMM2, PERSISTENT -------------------
// 1024 blocks x 512 thr (4/CU, full wave residency), grid-stride over
// the 1563 32-row tiles. Wt2 staged to LDS once per BLOCK (hoisted).
__global__ __launch_bounds__(512) void k_gather_gemm1(
    const int2* __restrict__ offs2, const uint2* __restrict__ pairs,
    const unsigned short* __restrict__ dense, const float* __restrict__ b1,
    const unsigned short* __restrict__ Wt2, unsigned short* __restrict__ out)
{
    __shared__ unsigned short Al[32 * 64];   // 4 KB
    __shared__ unsigned short Bl[64 * 64];   // 8 KB
    int t = threadIdx.x;
    {   // stage Wt2 once per block
        int u4 = t;
        int col = (u4 * 8) / 64, k = (u4 * 8) % 64;
        uint4 wv = ((const uint4*)Wt2)[u4];
        int byte = (col * 64 + k) * 2;
        byte ^= ((col & 7) << 4);
        *(uint4*)((char*)Bl + byte) = wv;
    }
    int w = t >> 6, d = t & 63;
    int l = t & 63;
    for (int vb = blockIdx.x; vb < GEMM_GRID; vb += PERSIST1) {
        int m0 = vb * 32;
        __syncthreads();                 // Al free (prev MFMA done) / Bl ready
        #pragma unroll 1
        for (int j = 0; j < 4; ++j) {
            int lr = w * 4 + j;
            int r = __builtin_amdgcn_readfirstlane(m0 + lr);
            float acc = 0.f;
            if (r < N_NODES) {
                int2 oe = offs2[r];
                int e0 = oe.x, e1 = oe.y;
                float a[8];
                a[0] = b1[d];
                #pragma unroll
                for (int i = 1; i < 8; ++i) a[i] = 0.f;
                int e = e0;
                for (; e + 8 <= e1; e += 8) {
                    uint2 p[8];
                    #pragma unroll
                    for (int i = 0; i < 8; ++i) p[i] = pairs[e + i];
                    unsigned v[8];
                    #pragma unroll
                    for (int i = 0; i < 8; ++i) v[i] = dense[(size_t)p[i].x * 64u + d];
                    #pragma unroll
                    for (int i = 0; i < 8; ++i)
                        a[i] = fmaf(__uint_as_float(p[i].y), bf2f(v[i]), a[i]);
                }
                if (e + 4 <= e1) {
                    uint2 p[4];
                    #pragma unroll
                    for (int i = 0; i < 4; ++i) p[i] = pairs[e + i];
                    unsigned v[4];
                    #pragma unroll
                    for (int i = 0; i < 4; ++i) v[i] = dense[(size_t)p[i].x * 64u + d];
                    #pragma unroll
                    for (int i = 0; i < 4; ++i)
                        a[i] = fmaf(__uint_as_float(p[i].y), bf2f(v[i]), a[i]);
                    e += 4;
                }
                for (; e < e1; ++e) {
                    uint2 p = pairs[e];
                    a[0] = fmaf(__uint_as_float(p.y),
                                bf2f(dense[(size_t)p.x * 64u + d]), a[0]);
                }
                acc = ((a[0] + a[1]) + (a[2] + a[3])) +
                      ((a[4] + a[5]) + (a[6] + a[7]));
                acc = fmaxf(acc, 0.f);           // relu (layer 1)
            }
            int byte = (lr * 64 + d) * 2;
            byte ^= ((lr & 7) << 4);
            *(unsigned short*)((char*)Al + byte) = f2bf(acc);
        }
        __syncthreads();
        int lr0 = (w & 1) * 16;
        int c0  = (w >> 1) * 16;
        int lrow = lr0 + (l & 15);
        int kb = (l >> 4) * 8;
        int col = c0 + (l & 15);
        f32x4 acc0 = {0.f, 0.f, 0.f, 0.f};
        #pragma unroll
        for (int kc = 0; kc < 2; ++kc) {
            int ka = kc * 32 + kb;
            int ab = (lrow * 64 + ka) * 2; ab ^= ((lrow & 7) << 4);
            int bb = (col * 64 + ka) * 2;  bb ^= ((col & 7) << 4);
            bf16x8 a = *(const bf16x8*)((const char*)Al + ab);
            bf16x8 b = *(const bf16x8*)((const char*)Bl + bb);
            acc0 = __builtin_amdgcn_mfma_f32_16x16x32_bf16(a, b, acc0, 0, 0, 0);
        }
        int grow0 = m0 + lr0 + (l >> 4) * 4;
        #pragma unroll
        for (int j = 0; j < 4; ++j) {
            int gr = grow0 + j;
            if (gr < N_NODES)
                out[(size_t)gr * 64 + col] = f2bf(acc0[j]);
        }
    }
}

// ---------------- gather2: PERSISTENT, 16-deep unroll, fp32 out -------
// 2048 blocks x 256 thr (8/CU), grid-stride over 12500 4-row tiles.
__global__ __launch_bounds__(256) void k_gather2(
    const int2* __restrict__ offs2, const uint2* __restrict__ pairs,
    const unsigned short* __restrict__ dense, const float* __restrict__ bias,
    float* __restrict__ outp)
{
    int t = threadIdx.x;
    int wv = t >> 6, d = t & 63;
    float bd = bias[d];
    for (int vb = blockIdx.x; vb < G2_TILES; vb += PERSIST2) {
        int r = __builtin_amdgcn_readfirstlane(vb * 4 + wv);
        int2 oe = offs2[r];
        int e0 = oe.x, e1 = oe.y;
        float a[16];
        a[0] = bd;
        #pragma unroll
        for (int i = 1; i < 16; ++i) a[i] = 0.f;
        int e = e0;
        for (; e + 16 <= e1; e += 16) {
            uint2 p[16];
            #pragma unroll
            for (int i = 0; i < 16; ++i) p[i] = pairs[e + i];
            unsigned v[16];
            #pragma unroll
            for (int i = 0; i < 16; ++i) v[i] = dense[(size_t)p[i].x * 64u + d];
            #pragma unroll
            for (int i = 0; i < 16; ++i)
                a[i] = fmaf(__uint_as_float(p[i].y), bf2f(v[i]), a[i]);
        }
        if (e + 8 <= e1) {
            uint2 p[8];
            #pragma unroll
            for (int i = 0; i < 8; ++i) p[i] = pairs[e + i];
            unsigned v[8];
            #pragma unroll
            for (int i = 0; i < 8; ++i) v[i] = dense[(size_t)p[i].x * 64u + d];
            #pragma unroll
            for (int i = 0; i < 8; ++i)
                a[i] = fmaf(__uint_as_float(p[i].y), bf2f(v[i]), a[i]);
            e += 8;
        }
        if (e + 4 <= e1) {
            uint2 p[4];
            #pragma unroll
            for (int i = 0; i < 4; ++i) p[i] = pairs[e + i];
            unsigned v[4];
            #pragma unroll
            for (int i = 0; i < 4; ++i) v[i] = dense[(size_t)p[i].x * 64u + d];
            #pragma unroll
            for (int i = 0; i < 4; ++i)
                a[i] = fmaf(__uint_as_float(p[i].y), bf2f(v[i]), a[i]);
            e += 4;
        }
        for (; e < e1; ++e) {
            uint2 p = pairs[e];
            a[0] = fmaf(__uint_as_float(p.y),
                        bf2f(dense[(size_t)p.x * 64u + d]), a[0]);
        }
        float s0 = ((a[0] + a[1]) + (a[2] + a[3])) +
                   ((a[4] + a[5]) + (a[6] + a[7]));
        float s1 = ((a[8] + a[9]) + (a[10] + a[11])) +
                   ((a[12] + a[13]) + (a[14] + a[15]));
        outp[(size_t)r * 64 + d] = s0 + s1;
    }
}

extern "C" void kernel_launch(void* const* d_in, const int* in_sizes, int n_in,
                              void* d_out, int out_size, void* d_ws, size_t ws_size,
                              hipStream_t stream)
{
    const float* x     = (const float*)d_in[0];
    const int*   erow  = (const int*)d_in[1];
    const int*   ecol  = (const int*)d_in[2];
    const float* eval_ = (const float*)d_in[3];
    const float* W1    = (const float*)d_in[4];
    const float* b1    = (const float*)d_in[5];
    const float* W2    = (const float*)d_in[6];
    const float* b2    = (const float*)d_in[7];
    float* out = (float*)d_out;

    // ws (~30 MB): pairs 8.03MB | bucketed 8.03MB | support bf16 6.4MB |
    // Wt1 | Wt2 | bcur | offs2 | support2 bf16 6.4MB
    uint2* pairs    = (uint2*)d_ws;
    uint2* bucketed = pairs + (size_t)NB * BCAP;
    unsigned short* support = (unsigned short*)(bucketed + (size_t)NB * BCAP);
    unsigned short* Wt1 = support + (size_t)N_NODES * 64;
    unsigned short* Wt2 = Wt1 + IN_DIM * HID_DIM;
    int*  bcur  = (int*)(Wt2 + HID_DIM * OUT_DIM);
    int2* offs2 = (int2*)(bcur + NB);          // NB=196 even -> 8B-aligned
    unsigned short* support2 = (unsigned short*)(offs2 + N_NODES + 2);

    // 5 dispatches
    k_prep<<<49, 256, 0, stream>>>(W1, Wt1, W2, Wt2, bcur);
    k_mega<<<NBLK_E + GEMM_GRID, 256, 0, stream>>>(
        erow, ecol, eval_, bcur, bucketed, x, Wt1, support);
    k_bfinal2<<<2 * NB, 256, 0, stream>>>(bcur, bucketed, pairs, offs2);
    k_gather_gemm1<<<PERSIST1, 512, 0, stream>>>(
        offs2, pairs, support, b1, Wt2, support2);
    k_gather2<<<PERSIST2, 256, 0, stream>>>(
        offs2, pairs, support2, b2, out);
}